// Round 6
// baseline (364.840 us; speedup 1.0000x reference)
//
#include <hip/hip_runtime.h>
#include <hip/hip_bf16.h>
#include <math.h>

// ---------------- constants ----------------
#define BSZ      8
#define TPREF    6144
#define CIN      8
#define DMODEL   256
#define DINNER   512
#define DSTATE   32
#define NHEADS   8
#define HEADDIM  64
#define CONVDIM  576
#define DPROJ    1096
#define ZXW      1088              // bf16 zx width (z 0..511 | xBC 512..1087)
#define NTOK     512
#define NVIS     384
#define TBWD     128
#define MFWD     (BSZ * NTOK)      // 4096 rows
#define MBWD     (BSZ * TBWD)      // 1024 rows
#define MALL     (MFWD + MBWD)     // 5120 rows

typedef float f32x4 __attribute__((ext_vector_type(4)));
typedef __bf16 bf16x8 __attribute__((ext_vector_type(8)));

__device__ __forceinline__ float silu_f(float x) { return x / (1.f + expf(-x)); }

#define ASYNC16(gp, lp) \
    __builtin_amdgcn_global_load_lds((const __attribute__((address_space(1))) void*)(gp), \
                                     (__attribute__((address_space(3))) void*)(lp), 16, 0, 0)

// ---------------- generic bf16 MFMA GEMM (NT): C[m,n] = sum_k A[m,k]*Bt[n,k] ----------------
// flags: 2=atomicAdd; 4=silu(v+bias)+bf16 store; 16=atomicAdd into h_all with (b,tok)->row remap
__global__ __launch_bounds__(256) void gemm_mfma(
    const __bf16* __restrict__ A, const __bf16* __restrict__ Bt,
    float* __restrict__ C, const float* __restrict__ bias,
    int N, int K, int ldc, int flags) {
    __shared__ char sm[16384];
    int tid = threadIdx.x;
    int m0 = blockIdx.y * 128, n0 = blockIdx.x * 128;
    int klen = K / gridDim.z;
    int kbeg = blockIdx.z * klen;
    int w = tid >> 6, l = tid & 63;
    int wm = w >> 1, wn = w & 1;
    int lm = l & 15, q = l >> 4;

    f32x4 acc[4][4];
    #pragma unroll
    for (int i = 0; i < 4; i++)
        #pragma unroll
        for (int j = 0; j < 4; j++) acc[i][j] = (f32x4)0.f;

    for (int k0 = 0; k0 < klen; k0 += 32) {
        int kb = kbeg + k0;
        #pragma unroll
        for (int i = 0; i < 2; i++) {
            int s = i * 256 + tid;
            ASYNC16(A + (size_t)(m0 + (s >> 2)) * K + kb + (s & 3) * 8, sm + s * 16);
        }
        #pragma unroll
        for (int i = 0; i < 2; i++) {
            int s = i * 256 + tid;
            ASYNC16(Bt + (size_t)(n0 + (s >> 2)) * K + kb + (s & 3) * 8, sm + 8192 + s * 16);
        }
        __syncthreads();
        bf16x8 af[4], bfr[4];
        #pragma unroll
        for (int mf = 0; mf < 4; mf++)
            af[mf] = *(const bf16x8*)(sm + (wm * 64 + mf * 16 + lm) * 64 + q * 16);
        #pragma unroll
        for (int nf = 0; nf < 4; nf++)
            bfr[nf] = *(const bf16x8*)(sm + 8192 + (wn * 64 + nf * 16 + lm) * 64 + q * 16);
        #pragma unroll
        for (int mf = 0; mf < 4; mf++)
            #pragma unroll
            for (int nf = 0; nf < 4; nf++)
                acc[mf][nf] = __builtin_amdgcn_mfma_f32_16x16x32_bf16(af[mf], bfr[nf], acc[mf][nf], 0, 0, 0);
        __syncthreads();
    }

    #pragma unroll
    for (int mf = 0; mf < 4; mf++) {
        int mbase = m0 + wm * 64 + mf * 16 + q * 4;
        #pragma unroll
        for (int nf = 0; nf < 4; nf++) {
            int n = n0 + wn * 64 + nf * 16 + lm;
            if (n < N) {
                #pragma unroll
                for (int r = 0; r < 4; r++) {
                    float v = acc[mf][nf][r];
                    if (flags & 4) {
                        v = silu_f(v + bias[n]);
                        ((__bf16*)C)[(size_t)(mbase + r) * ldc + n] = (__bf16)v;
                    } else if (flags & 16) {
                        int mm = mbase + r;
                        int bb = mm / NVIS, tk = mm - bb * NVIS;   // m = b*384+tok
                        atomicAdd(C + ((size_t)(bb * NTOK + tk)) * 256 + n, v);
                    } else if (flags & 2) {
                        atomicAdd(C + (size_t)(mbase + r) * ldc + n, v);
                    } else {
                        C[(size_t)(mbase + r) * ldc + n] = v;
                    }
                }
            }
        }
    }
}

// ---------------- pre-conv GEMM with fused im2row ----------------
__global__ __launch_bounds__(256) void preconv_gemm(
    const float* __restrict__ xp, const __bf16* __restrict__ WpreT,
    const float* __restrict__ bias, __bf16* __restrict__ Apatch) {
    __shared__ char sm[32768];   // A: [2][128][32]bf16 = 16KB @0, B: same @16384
    int tid = threadIdx.x;
    int m0 = blockIdx.y * 128, n0 = blockIdx.x * 128;
    int w = tid >> 6, l = tid & 63;
    int wm = w >> 1, wn = w & 1, lm = l & 15, q = l >> 4;

    #pragma unroll
    for (int i = 0; i < 4; i++) {
        int s = i * 256 + tid;
        int kh = s >> 9, row = (s & 511) >> 2, within = s & 3;
        ASYNC16(WpreT + (size_t)(n0 + row) * 64 + kh * 32 + within * 8, sm + 16384 + s * 16);
    }
    if (tid < 128) {
        int m = m0 + tid;
        int b = m / TPREF, t = m - b * TPREF;
        __bf16 d[64];
        #pragma unroll
        for (int j = 40; j < 64; j++) d[j] = (__bf16)0.f;
        #pragma unroll
        for (int k = 0; k < 5; k++) {
            int tt = t - 2 + k;
            bool ok = (tt >= 0) && (tt < TPREF);
            const float* s = xp + ((size_t)b * TPREF + tt) * 8;
            #pragma unroll
            for (int i = 0; i < 8; i++)
                d[i * 5 + k] = ok ? (__bf16)s[i] : (__bf16)0.f;
        }
        uint4* o0 = (uint4*)(sm + tid * 64);
        uint4* o1 = (uint4*)(sm + 8192 + tid * 64);
        #pragma unroll
        for (int k = 0; k < 4; k++) { o0[k] = ((const uint4*)d)[k]; o1[k] = ((const uint4*)d)[4 + k]; }
    }
    __syncthreads();

    f32x4 acc[4][4];
    #pragma unroll
    for (int i = 0; i < 4; i++)
        #pragma unroll
        for (int j = 0; j < 4; j++) acc[i][j] = (f32x4)0.f;
    #pragma unroll
    for (int kh = 0; kh < 2; kh++) {
        bf16x8 af[4], bfr[4];
        #pragma unroll
        for (int mf = 0; mf < 4; mf++)
            af[mf] = *(const bf16x8*)(sm + kh * 8192 + (wm * 64 + mf * 16 + lm) * 64 + q * 16);
        #pragma unroll
        for (int nf = 0; nf < 4; nf++)
            bfr[nf] = *(const bf16x8*)(sm + 16384 + kh * 8192 + (wn * 64 + nf * 16 + lm) * 64 + q * 16);
        #pragma unroll
        for (int mf = 0; mf < 4; mf++)
            #pragma unroll
            for (int nf = 0; nf < 4; nf++)
                acc[mf][nf] = __builtin_amdgcn_mfma_f32_16x16x32_bf16(af[mf], bfr[nf], acc[mf][nf], 0, 0, 0);
    }
    #pragma unroll
    for (int mf = 0; mf < 4; mf++) {
        int mbase = m0 + wm * 64 + mf * 16 + q * 4;
        #pragma unroll
        for (int nf = 0; nf < 4; nf++) {
            int n = n0 + wn * 64 + nf * 16 + lm;
            #pragma unroll
            for (int r = 0; r < 4; r++) {
                float v = silu_f(acc[mf][nf][r] + bias[n]);
                Apatch[(size_t)(mbase + r) * 256 + n] = (__bf16)v;
            }
        }
    }
}

// ---------------- final GEMM: hcat gather fused; split-K 4 (dir x k-half) ----------------
__global__ __launch_bounds__(256) void final_gemm(
    const float* __restrict__ h_all, const __bf16* __restrict__ poT,
    float* __restrict__ out) {
    __shared__ __bf16 Asm_[128][40];
    __shared__ char Bsm[8192];
    int tid = threadIdx.x;
    int m0 = blockIdx.y * 128;
    int z = blockIdx.z;                 // 0..3
    int dir = z >> 1, kh = z & 1;
    int koff = kh * 128;
    int w = tid >> 6, l = tid & 63;
    int wm = w >> 1, wn_ = w & 1, lm = l & 15, q = l >> 4;
    f32x4 acc[4][4];
    #pragma unroll
    for (int i = 0; i < 4; i++)
        #pragma unroll
        for (int j = 0; j < 4; j++) acc[i][j] = (f32x4)0.f;

    int r = tid >> 1, half = tid & 1;
    int m = m0 + r;
    int b = m >> 7, jj = m & 127;
    size_t arow = (dir == 0) ? ((size_t)(b * NTOK + NVIS + jj) * 256)
                             : ((size_t)MFWD * 256 + (size_t)(b * TBWD + (TBWD - 1 - jj)) * 256);
    for (int k0 = 0; k0 < 128; k0 += 32) {
        {
            const float4* sp = (const float4*)(h_all + arow + koff + k0 + half * 16);
            float4 v0 = sp[0], v1 = sp[1], v2 = sp[2], v3 = sp[3];
            union { uint4 u; __bf16 hh[8]; } d0, d1;
            d0.hh[0] = (__bf16)v0.x; d0.hh[1] = (__bf16)v0.y; d0.hh[2] = (__bf16)v0.z; d0.hh[3] = (__bf16)v0.w;
            d0.hh[4] = (__bf16)v1.x; d0.hh[5] = (__bf16)v1.y; d0.hh[6] = (__bf16)v1.z; d0.hh[7] = (__bf16)v1.w;
            d1.hh[0] = (__bf16)v2.x; d1.hh[1] = (__bf16)v2.y; d1.hh[2] = (__bf16)v2.z; d1.hh[3] = (__bf16)v2.w;
            d1.hh[4] = (__bf16)v3.x; d1.hh[5] = (__bf16)v3.y; d1.hh[6] = (__bf16)v3.z; d1.hh[7] = (__bf16)v3.w;
            *(uint4*)&Asm_[r][half * 16] = d0.u;
            *(uint4*)&Asm_[r][half * 16 + 8] = d1.u;
        }
        #pragma unroll
        for (int i = 0; i < 2; i++) {
            int s = i * 256 + tid;
            ASYNC16(poT + (size_t)(s >> 2) * 512 + dir * 256 + koff + k0 + (s & 3) * 8, Bsm + s * 16);
        }
        __syncthreads();
        bf16x8 af[4], bfr[4];
        #pragma unroll
        for (int mf = 0; mf < 4; mf++)
            af[mf] = *(const bf16x8*)&Asm_[wm * 64 + mf * 16 + lm][q * 8];
        #pragma unroll
        for (int nf = 0; nf < 4; nf++)
            bfr[nf] = *(const bf16x8*)(Bsm + (wn_ * 64 + nf * 16 + lm) * 64 + q * 16);
        #pragma unroll
        for (int mf = 0; mf < 4; mf++)
            #pragma unroll
            for (int nf = 0; nf < 4; nf++)
                acc[mf][nf] = __builtin_amdgcn_mfma_f32_16x16x32_bf16(af[mf], bfr[nf], acc[mf][nf], 0, 0, 0);
        __syncthreads();
    }
    #pragma unroll
    for (int mf = 0; mf < 4; mf++) {
        int mbase = m0 + wm * 64 + mf * 16 + q * 4;
        #pragma unroll
        for (int nf = 0; nf < 4; nf++) {
            int n = wn_ * 64 + nf * 16 + lm;
            #pragma unroll
            for (int rr = 0; rr < 4; rr++)
                atomicAdd(out + (size_t)(mbase + rr) * 128 + n, acc[mf][nf][rr]);
        }
    }
}

// ---------------- inproj GEMM with FUSED rmsnorm ----------------
// A = bf16(h * norm_w) staged from fp32 h; ss accumulated during staging; rs applied at epilogue.
__global__ __launch_bounds__(256) void gemm_inproj(
    const float* __restrict__ h, const float* __restrict__ nwf, const float* __restrict__ nwb,
    const __bf16* __restrict__ ipTf, const __bf16* __restrict__ ipTb,
    __bf16* __restrict__ zxb, float* __restrict__ dtc) {
    __shared__ char sm[16384];
    __shared__ float rsl[128];
    int tid = threadIdx.x;
    int m0 = blockIdx.y * 128, n0 = blockIdx.x * 128;
    const __bf16* Bt = (m0 >= MFWD) ? ipTb : ipTf;
    const float* nw = (m0 >= MFWD) ? nwb : nwf;
    int w = tid >> 6, l = tid & 63;
    int wm = w >> 1, wn = w & 1, lm = l & 15, q = l >> 4;
    f32x4 acc[4][4];
    #pragma unroll
    for (int i = 0; i < 4; i++)
        #pragma unroll
        for (int j = 0; j < 4; j++) acc[i][j] = (f32x4)0.f;

    int ar = tid >> 1, aseg = tid & 1;
    const float* hrow = h + (size_t)(m0 + ar) * 256;
    float ss = 0.f;

    for (int k0 = 0; k0 < 256; k0 += 32) {
        {   // A stage: this thread covers 16 cols of its row; accumulate ss (over raw h)
            int cb = k0 + aseg * 16;
            float4 v0 = *(const float4*)(hrow + cb);
            float4 v1 = *(const float4*)(hrow + cb + 4);
            float4 v2 = *(const float4*)(hrow + cb + 8);
            float4 v3 = *(const float4*)(hrow + cb + 12);
            float4 w0 = *(const float4*)(nw + cb);
            float4 w1 = *(const float4*)(nw + cb + 4);
            float4 w2 = *(const float4*)(nw + cb + 8);
            float4 w3 = *(const float4*)(nw + cb + 12);
            ss += v0.x * v0.x + v0.y * v0.y + v0.z * v0.z + v0.w * v0.w
                + v1.x * v1.x + v1.y * v1.y + v1.z * v1.z + v1.w * v1.w
                + v2.x * v2.x + v2.y * v2.y + v2.z * v2.z + v2.w * v2.w
                + v3.x * v3.x + v3.y * v3.y + v3.z * v3.z + v3.w * v3.w;
            union { uint4 u; __bf16 hh[8]; } d0, d1;
            d0.hh[0] = (__bf16)(v0.x * w0.x); d0.hh[1] = (__bf16)(v0.y * w0.y);
            d0.hh[2] = (__bf16)(v0.z * w0.z); d0.hh[3] = (__bf16)(v0.w * w0.w);
            d0.hh[4] = (__bf16)(v1.x * w1.x); d0.hh[5] = (__bf16)(v1.y * w1.y);
            d0.hh[6] = (__bf16)(v1.z * w1.z); d0.hh[7] = (__bf16)(v1.w * w1.w);
            d1.hh[0] = (__bf16)(v2.x * w2.x); d1.hh[1] = (__bf16)(v2.y * w2.y);
            d1.hh[2] = (__bf16)(v2.z * w2.z); d1.hh[3] = (__bf16)(v2.w * w2.w);
            d1.hh[4] = (__bf16)(v3.x * w3.x); d1.hh[5] = (__bf16)(v3.y * w3.y);
            d1.hh[6] = (__bf16)(v3.z * w3.z); d1.hh[7] = (__bf16)(v3.w * w3.w);
            *(uint4*)(sm + ar * 64 + aseg * 32) = d0.u;
            *(uint4*)(sm + ar * 64 + aseg * 32 + 16) = d1.u;
        }
        #pragma unroll
        for (int i = 0; i < 2; i++) {
            int s = i * 256 + tid;
            ASYNC16(Bt + (size_t)(n0 + (s >> 2)) * 256 + k0 + (s & 3) * 8, sm + 8192 + s * 16);
        }
        __syncthreads();
        bf16x8 af[4], bfr[4];
        #pragma unroll
        for (int mf = 0; mf < 4; mf++)
            af[mf] = *(const bf16x8*)(sm + (wm * 64 + mf * 16 + lm) * 64 + q * 16);
        #pragma unroll
        for (int nf = 0; nf < 4; nf++)
            bfr[nf] = *(const bf16x8*)(sm + 8192 + (wn * 64 + nf * 16 + lm) * 64 + q * 16);
        #pragma unroll
        for (int mf = 0; mf < 4; mf++)
            #pragma unroll
            for (int nf = 0; nf < 4; nf++)
                acc[mf][nf] = __builtin_amdgcn_mfma_f32_16x16x32_bf16(af[mf], bfr[nf], acc[mf][nf], 0, 0, 0);
        __syncthreads();
    }
    ss += __shfl_xor(ss, 1);
    if (aseg == 0) rsl[ar] = rsqrtf(ss * (1.f / 256.f) + 1e-5f);
    __syncthreads();

    #pragma unroll
    for (int mf = 0; mf < 4; mf++) {
        int lrow = wm * 64 + mf * 16 + q * 4;
        int mbase = m0 + lrow;
        #pragma unroll
        for (int nf = 0; nf < 4; nf++) {
            int n = n0 + wn * 64 + nf * 16 + lm;
            #pragma unroll
            for (int r = 0; r < 4; r++) {
                float v = acc[mf][nf][r] * rsl[lrow + r];
                if (n < ZXW) zxb[(size_t)(mbase + r) * ZXW + n] = (__bf16)v;
                else if (n < DPROJ) dtc[(size_t)(mbase + r) * 8 + (n - ZXW)] = v;
            }
        }
    }
}

// ---------------- outproj GEMM with FUSED gatednorm ----------------
// A = bf16(y*silu(z)*gnorm_w) staged from ysD/zxb; ss over y*silu(z); rs at epilogue; residual +=
__global__ __launch_bounds__(256) void gemm_outproj(
    const __bf16* __restrict__ ysD, const __bf16* __restrict__ zxb,
    const float* __restrict__ gwf, const float* __restrict__ gwb,
    const __bf16* __restrict__ opTf, const __bf16* __restrict__ opTb,
    float* __restrict__ C, int layer) {
    __shared__ char sm[16384];
    __shared__ float rsl[128];
    int tid = threadIdx.x;
    int yb = blockIdx.y;
    int m0 = (layer == 0) ? yb * 128
                          : ((yb < 8) ? (yb * 512 + 384) : (MFWD + (yb - 8) * 128));
    int n0 = blockIdx.x * 128;
    const __bf16* Bt = (m0 >= MFWD) ? opTb : opTf;
    const float* gw = (m0 >= MFWD) ? gwb : gwf;
    int w = tid >> 6, l = tid & 63;
    int wm = w >> 1, wn = w & 1, lm = l & 15, q = l >> 4;
    f32x4 acc[4][4];
    #pragma unroll
    for (int i = 0; i < 4; i++)
        #pragma unroll
        for (int j = 0; j < 4; j++) acc[i][j] = (f32x4)0.f;

    int ar = tid >> 1, aseg = tid & 1;
    const __bf16* yrow = ysD + (size_t)(m0 + ar) * 512;
    const __bf16* zrow = zxb + (size_t)(m0 + ar) * ZXW;
    float ss = 0.f;

    for (int k0 = 0; k0 < 512; k0 += 32) {
        {   // A stage: gate + weight, ss over x = y*silu(z)
            int cb = k0 + aseg * 16;
            union { uint4 u; __bf16 hh[8]; } y0, y1, z0, z1, d0, d1;
            y0.u = *(const uint4*)(yrow + cb);     y1.u = *(const uint4*)(yrow + cb + 8);
            z0.u = *(const uint4*)(zrow + cb);     z1.u = *(const uint4*)(zrow + cb + 8);
            union { float4 v[4]; float f[16]; } g;   // guaranteed-contiguous gate weights
            g.v[0] = *(const float4*)(gw + cb);
            g.v[1] = *(const float4*)(gw + cb + 4);
            g.v[2] = *(const float4*)(gw + cb + 8);
            g.v[3] = *(const float4*)(gw + cb + 12);
            #pragma unroll
            for (int j = 0; j < 8; j++) {
                float x = (float)y0.hh[j] * silu_f((float)z0.hh[j]);
                ss += x * x;
                d0.hh[j] = (__bf16)(x * g.f[j]);
            }
            #pragma unroll
            for (int j = 0; j < 8; j++) {
                float x = (float)y1.hh[j] * silu_f((float)z1.hh[j]);
                ss += x * x;
                d1.hh[j] = (__bf16)(x * g.f[8 + j]);
            }
            *(uint4*)(sm + ar * 64 + aseg * 32) = d0.u;
            *(uint4*)(sm + ar * 64 + aseg * 32 + 16) = d1.u;
        }
        #pragma unroll
        for (int i = 0; i < 2; i++) {
            int s = i * 256 + tid;
            ASYNC16(Bt + (size_t)(n0 + (s >> 2)) * 512 + k0 + (s & 3) * 8, sm + 8192 + s * 16);
        }
        __syncthreads();
        bf16x8 af[4], bfr[4];
        #pragma unroll
        for (int mf = 0; mf < 4; mf++)
            af[mf] = *(const bf16x8*)(sm + (wm * 64 + mf * 16 + lm) * 64 + q * 16);
        #pragma unroll
        for (int nf = 0; nf < 4; nf++)
            bfr[nf] = *(const bf16x8*)(sm + 8192 + (wn * 64 + nf * 16 + lm) * 64 + q * 16);
        #pragma unroll
        for (int mf = 0; mf < 4; mf++)
            #pragma unroll
            for (int nf = 0; nf < 4; nf++)
                acc[mf][nf] = __builtin_amdgcn_mfma_f32_16x16x32_bf16(af[mf], bfr[nf], acc[mf][nf], 0, 0, 0);
        __syncthreads();
    }
    ss += __shfl_xor(ss, 1);
    if (aseg == 0) rsl[ar] = rsqrtf(ss * (1.f / 512.f) + 1e-5f);
    __syncthreads();

    #pragma unroll
    for (int mf = 0; mf < 4; mf++) {
        int lrow = wm * 64 + mf * 16 + q * 4;
        int mbase = m0 + lrow;
        #pragma unroll
        for (int nf = 0; nf < 4; nf++) {
            int n = n0 + wn * 64 + nf * 16 + lm;
            #pragma unroll
            for (int r = 0; r < 4; r++) {
                size_t ci = (size_t)(mbase + r) * DMODEL + n;
                C[ci] += acc[mf][nf][r] * rsl[lrow + r];
            }
        }
    }
}

// ---------------- segmented prep kernel (all coalesced) ----------------
// WtT 256 | inprojT 1152 | outprojT 512 | poT 64 | WpreT 64 | dout 512 | hinit 5120
__global__ void prep_all(const float* __restrict__ pre_conv_w, const float* __restrict__ patch_w,
                         const float* __restrict__ ip0, const float* __restrict__ ip1,
                         const float* __restrict__ op0, const float* __restrict__ op1,
                         const float* __restrict__ pow_, const float* __restrict__ pob,
                         const float* __restrict__ y_aux, const float* __restrict__ aux_w,
                         const float* __restrict__ aux_b,
                         const float* __restrict__ patch_b, const float* __restrict__ mtok,
                         __bf16* __restrict__ WpreT, __bf16* __restrict__ WtT,
                         __bf16* __restrict__ inprojT, __bf16* __restrict__ outprojT,
                         __bf16* __restrict__ poT, float* __restrict__ dout,
                         float* __restrict__ h_all) {
    __shared__ float tile[32][33];
    int bx = blockIdx.x, tid = threadIdx.x;
    int tx = tid & 31, ty = tid >> 5;
    if (bx < 256) {
        int o = bx, c = tid;
        float f[16];
        const float4* s = (const float4*)(patch_w + (size_t)o * 4096 + c * 16);
        #pragma unroll
        for (int j = 0; j < 4; j++) *(float4*)&f[j * 4] = s[j];
        #pragma unroll
        for (int k = 0; k < 16; k++)
            WtT[(size_t)o * 4096 + k * 256 + c] = (__bf16)f[k];
        return;
    }
    bx -= 256;
    if (bx < 1152) {
        int seg = bx / 288, rem = bx % 288;
        int n0 = (rem / 8) * 32, k0 = (rem % 8) * 32;
        const float* src = (seg < 2 ? ip0 : ip1) + (size_t)(seg & 1) * 256 * DPROJ;
        #pragma unroll
        for (int j = 0; j < 4; j++) {
            int r = ty + j * 8;
            int n = n0 + tx;
            tile[r][tx] = (n < DPROJ) ? src[(size_t)(k0 + r) * DPROJ + n] : 0.f;
        }
        __syncthreads();
        __bf16* dst = inprojT + (size_t)seg * 1152 * 256;
        #pragma unroll
        for (int j = 0; j < 4; j++) {
            int r = ty + j * 8;
            dst[(size_t)(n0 + r) * 256 + k0 + tx] = (__bf16)tile[tx][r];
        }
        return;
    }
    bx -= 1152;
    if (bx < 512) {
        int s = bx / 128, rem = bx % 128;
        int n0 = (rem / 16) * 32, k0 = (rem % 16) * 32;
        const float* src = (s < 2 ? op0 : op1) + (size_t)(s & 1) * DINNER * DMODEL;
        #pragma unroll
        for (int j = 0; j < 4; j++) {
            int r = ty + j * 8;
            tile[r][tx] = src[(size_t)(k0 + r) * 256 + n0 + tx];
        }
        __syncthreads();
        __bf16* dst = outprojT + (size_t)s * 256 * 512;
        #pragma unroll
        for (int j = 0; j < 4; j++) {
            int r = ty + j * 8;
            dst[(size_t)(n0 + r) * 512 + k0 + tx] = (__bf16)tile[tx][r];
        }
        return;
    }
    bx -= 512;
    if (bx < 64) {
        int n0 = (bx / 16) * 32, k0 = (bx % 16) * 32;
        #pragma unroll
        for (int j = 0; j < 4; j++) {
            int r = ty + j * 8;
            tile[r][tx] = pow_[(size_t)(k0 + r) * 128 + n0 + tx];
        }
        __syncthreads();
        #pragma unroll
        for (int j = 0; j < 4; j++) {
            int r = ty + j * 8;
            poT[(size_t)(n0 + r) * 512 + k0 + tx] = (__bf16)tile[tx][r];
        }
        return;
    }
    bx -= 64;
    if (bx < 64) {
        int idx = bx * 256 + tid;
        int o = idx >> 6, kk = idx & 63;
        WpreT[idx] = (kk < 40) ? (__bf16)pre_conv_w[o * 40 + kk] : (__bf16)0.f;
        return;
    }
    bx -= 64;
    if (bx < 512) {
        int idx = bx * 256 + tid;
        dout[idx] = pob[idx & 127];
        return;
    }
    bx -= 512;
    {   // h_all init: visible fwd rows = patch_b+aux (GEMM atomically adds patch term);
        // masked fwd rows and all bwd rows = mask_token+aux
        int row = bx, o = tid;
        int b; bool masked;
        if (row < MFWD) { b = row >> 9; int tok = row & 511; masked = (tok >= NVIS); }
        else { b = (row - MFWD) >> 7; masked = true; }
        float acc = aux_b[o];
        #pragma unroll
        for (int i = 0; i < 16; i++) acc += y_aux[b * 16 + i] * aux_w[i * 256 + o];
        float v = (masked ? mtok[o] : patch_b[o]) + silu_f(acc);
        h_all[(size_t)row * 256 + o] = v;
    }
}

// ---------------- chunked SSD scan phase A with fused depthwise conv: 4 waves/block ----------------
// grid (80, 8). Stages raw X/BC slices from zxb cooperatively (uint4), conv k=4 + silu in-block.
__global__ __launch_bounds__(256) void scan_local(
    const __bf16* __restrict__ zxb,
    const float* __restrict__ cwf, const float* __restrict__ cbf,
    const float* __restrict__ cwb, const float* __restrict__ cbb,
    const float* __restrict__ dtc,
    const float* __restrict__ dtbf, const float* __restrict__ dtbb,
    const float* __restrict__ Alogf, const float* __restrict__ Alogb,
    const float* __restrict__ Dpf, const float* __restrict__ Dpb,
    __bf16* __restrict__ ysD,
    __bf16* __restrict__ ChatF, __bf16* __restrict__ ChatB,
    float* __restrict__ dSF, float* __restrict__ dSB,
    float* __restrict__ DcsF, float* __restrict__ DcsB, int layer) {
    int id = blockIdx.x, hd = blockIdx.y;
    int b, c, T, NC; size_t rowbase;
    __bf16* Chat; float *dS, *Dcs;
    const float *dtb, *Alog, *Dp, *cw, *cb;
    if (id < 64) { b = id >> 3; c = id & 7; T = NTOK; NC = 8; rowbase = (size_t)b * NTOK;
                   Chat = ChatF; dS = dSF; Dcs = DcsF;
                   dtb = dtbf; Alog = Alogf; Dp = Dpf; cw = cwf; cb = cbf; }
    else { int i2 = id - 64; b = i2 >> 1; c = i2 & 1; T = TBWD; NC = 2;
           rowbase = (size_t)MFWD + (size_t)b * TBWD;
           Chat = ChatB; dS = dSB; Dcs = DcsB;
           dtb = dtbb; Alog = Alogb; Dp = Dpb; cw = cwb; cb = cbb; }
    bool skipY = (layer == 1) && (id < 64) && (c < 6);
    int bh = b * 8 + hd;
    int t0 = c * 64;
    int tid = threadIdx.x;
    int w = tid >> 6, l = tid & 63;
    int lm = l & 15, q = l >> 4;
    float A = -expf(Alog[hd]);
    float Dh = Dp[hd];

    __shared__ char smem[40704];
    __bf16 (*Xl)[72]  = (__bf16(*)[72])(smem);            // Xl[ch][t] post-conv
    __bf16 (*BCl)[72] = (__bf16(*)[72])(smem + 9216);     // BCl[t][ch] post-conv
    __bf16 (*Pl)[72]  = (__bf16(*)[72])(smem + 9216);     // overwrites BCl after reads done
    __bf16 (*Wbl)[72] = (__bf16(*)[72])(smem + 18432);
    float* lcs = (float*)(smem + 23040);
    float* dts = (float*)(smem + 23296);
    __bf16 (*xraw)[64] = (__bf16(*)[64])(smem + 23552);   // 67x64 raw X (this head)
    __bf16 (*braw)[64] = (__bf16(*)[64])(smem + 32128);   // 67x64 raw BC

    // ---- stage raw slices: 1072 uint4 chunks over 256 threads ----
    for (int s = tid; s < 1072; s += 256) {
        int arr = (s >= 536) ? 1 : 0;
        int s2 = s - arr * 536;
        int r = s2 >> 3, seg = s2 & 7;
        int t = t0 - 3 + r;
        uint4 v = make_uint4(0u, 0u, 0u, 0u);
        if (t >= 0) {
            size_t col = arr ? (size_t)(1024 + seg * 8) : (size_t)(DINNER + hd * 64 + seg * 8);
            v = *(const uint4*)(zxb + (rowbase + t) * (size_t)ZXW + col);
        }
        if (arr) *(uint4*)&braw[r][seg * 8] = v;
        else     *(uint4*)&xraw[r][seg * 8] = v;
    }
    __syncthreads();

    // ---- conv X: ch = lane, t-quarter = wave; pack 16 outputs -> Xl[ch][t] ----
    {
        int cX = hd * 64 + l;
        float w0 = cw[cX * 4], w1 = cw[cX * 4 + 1], w2 = cw[cX * 4 + 2], w3 = cw[cX * 4 + 3];
        float cbv = cb[cX];
        int tb = w * 16;
        float a0 = (float)xraw[tb][l], a1 = (float)xraw[tb + 1][l], a2 = (float)xraw[tb + 2][l];
        union { uint4 u; __bf16 h[8]; } p0, p1;
        #pragma unroll
        for (int j = 0; j < 16; j++) {
            float a3 = (float)xraw[tb + j + 3][l];
            float acc = cbv + w0 * a0 + w1 * a1 + w2 * a2 + w3 * a3;
            if (j < 8) p0.h[j] = (__bf16)silu_f(acc);
            else       p1.h[j - 8] = (__bf16)silu_f(acc);
            a0 = a1; a1 = a2; a2 = a3;
        }
        *(uint4*)&Xl[l][tb]     = p0.u;
        *(uint4*)&Xl[l][tb + 8] = p1.u;
    }
    // ---- conv BC: ch = lane, t-quarter = wave -> BCl[t][ch] (transposed, scalar stores) ----
    {
        int cc = 512 + l;
        float w0 = cw[cc * 4], w1 = cw[cc * 4 + 1], w2 = cw[cc * 4 + 2], w3 = cw[cc * 4 + 3];
        float cbv = cb[cc];
        int tb = w * 16;
        float a0 = (float)braw[tb][l], a1 = (float)braw[tb + 1][l], a2 = (float)braw[tb + 2][l];
        #pragma unroll
        for (int j = 0; j < 16; j++) {
            float a3 = (float)braw[tb + j + 3][l];
            float acc = cbv + w0 * a0 + w1 * a1 + w2 * a2 + w3 * a3;
            BCl[tb + j][l] = (__bf16)silu_f(acc);
            a0 = a1; a1 = a2; a2 = a3;
        }
    }
    // ---- per-token dt + cumulative log-decay (redundant per wave; lane = token) ----
    float xdt = dtc[(rowbase + t0 + l) * 8 + hd] + dtb[hd];
    float dtv = (xdt > 20.f) ? xdt : log1pf(expf(xdt));
    float lc = A * dtv;
    #pragma unroll
    for (int off = 1; off < 64; off <<= 1) {
        float o = __shfl_up(lc, off);
        if (l >= off) lc += o;
    }
    float lc63 = __shfl(lc, 63);
    float wj = expf(lc63 - lc) * dtv;
    float eli = expf(lc);
    if (w == 0) {
        lcs[l] = lc; dts[l] = dtv;
        if (l == 0) Dcs[bh * NC + c] = expf(lc63);
    }
    __syncthreads();   // conv outputs + lcs/dts visible

    // ---- Chat write (wave w: channel group w*8..w*8+7 of C part) ----
    if (!skipY) {
        union { uint4 u; __bf16 h[8]; } s, d;
        s.u = *(const uint4*)&BCl[l][32 + w * 8];
        #pragma unroll
        for (int j = 0; j < 8; j++) d.h[j] = (__bf16)(eli * (float)s.h[j]);
        *(uint4*)(Chat + ((size_t)(bh * NC + c) * 64 + l) * 32 + w * 8) = d.u;
    }
    // ---- Wbl[n][t] build (wave w: n group w*8..w*8+7) ----
    {
        union { uint4 u; __bf16 h[8]; } s;
        s.u = *(const uint4*)&BCl[l][w * 8];
        #pragma unroll
        for (int j = 0; j < 8; j++) Wbl[w * 8 + j][l] = (__bf16)(wj * (float)s.h[j]);
    }
    // ---- P-phase register loads (must complete before Pl overwrites BCl) ----
    bf16x8 cfr, bfr[4];
    if (!skipY) {
        cfr = *(const bf16x8*)&BCl[w * 16 + lm][32 + q * 8];
        #pragma unroll
        for (int tj = 0; tj < 4; tj++)
            if (tj <= w) bfr[tj] = *(const bf16x8*)&BCl[tj * 16 + lm][q * 8];
    }
    __syncthreads();   // all BCl reads done; Wbl complete

    if (!skipY) {
        float lci[4];
        #pragma unroll
        for (int r = 0; r < 4; r++) lci[r] = lcs[w * 16 + q * 4 + r];
        #pragma unroll
        for (int tj = 0; tj < 4; tj++) {
            if (tj > w) {
                #pragma unroll
                for (int r = 0; r < 4; r++) Pl[w * 16 + q * 4 + r][tj * 16 + lm] = (__bf16)0.f;
                continue;
            }
            f32x4 g = __builtin_amdgcn_mfma_f32_16x16x32_bf16(cfr, bfr[tj], (f32x4)0.f, 0, 0, 0);
            int j = tj * 16 + lm;
            float lcj = lcs[j], dtj = dts[j];
            #pragma unroll
            for (int r = 0; r < 4; r++) {
                int i = w * 16 + q * 4 + r;
                float v = (j <= i) ? g[r] * expf(lci[r] - lcj) * dtj : 0.f;
                if (j == i) v += Dh;
                Pl[i][j] = (__bf16)v;
            }
        }
    }
    __syncthreads();   // Pl ready

    bf16x8 xf0[4], xf1[4];
    #pragma unroll
    for (int t4 = 0; t4 < 4; t4++) {
        xf0[t4] = *(const bf16x8*)&Xl[t4 * 16 + lm][q * 8];
        xf1[t4] = *(const bf16x8*)&Xl[t4 * 16 + lm][32 + q * 8];
    }
    if (!skipY) {
        bf16x8 pf0 = *(const bf16x8*)&Pl[w * 16 + lm][q * 8];
        bf16x8 pf1 = *(const bf16x8*)&Pl[w * 16 + lm][32 + q * 8];
        #pragma unroll
        for (int tp = 0; tp < 4; tp++) {
            f32x4 y = __builtin_amdgcn_mfma_f32_16x16x32_bf16(pf0, xf0[tp], (f32x4)0.f, 0, 0, 0);
            y = __builtin_amdgcn_mfma_f32_16x16x32_bf16(pf1, xf1[tp], y, 0, 0, 0);
            #pragma unroll
            for (int r = 0; r < 4; r++) {
                int i = w * 16 + q * 4 + r;
                ysD[(rowbase + t0 + i) * DINNER + hd * 64 + tp * 16 + lm] = (__bf16)y[r];
            }
        }
    }
    // ---- dS (wave w = tp) ----
    bf16x8 wf0[2], wf1[2];
    #pragma unroll
    for (int tn = 0; tn < 2; tn++) {
        wf0[tn] = *(const bf16x8*)&Wbl[tn * 16 + lm][q * 8];
        wf1[tn] = *(const bf16x8*)&Wbl[tn * 16 + lm][32 + q * 8];
    }
    float* dso = dS + (size_t)(bh * NC + c) * 2048;
    #pragma unroll
    for (int tn = 0; tn < 2; tn++) {
        f32x4 s = __builtin_amdgcn_mfma_f32_16x16x32_bf16(xf0[w], wf0[tn], (f32x4)0.f, 0, 0, 0);
        s = __builtin_amdgcn_mfma_f32_16x16x32_bf16(xf1[w], wf1[tn], s, 0, 0, 0);
        #pragma unroll
        for (int r = 0; r < 4; r++) {
            int pp = w * 16 + q * 4 + r, nn = tn * 16 + lm;
            dso[pp * 32 + nn] = s[r];
        }
    }
}

// ---------------- scan tail: recurrence + cross-chunk Y add ----------------
__global__ __launch_bounds__(256) void scan_tail(
    const float* __restrict__ dSF, const float* __restrict__ dSB,
    const float* __restrict__ DcsF, const float* __restrict__ DcsB,
    const __bf16* __restrict__ ChatF, const __bf16* __restrict__ ChatB,
    __bf16* __restrict__ ysD, int layer) {
    int blk = blockIdx.x;
    int dir = blk >= 64;
    int bh = blk & 63;
    int NC = dir ? 2 : 8;
    int T = dir ? TBWD : NTOK;
    int b = bh >> 3, hd = bh & 7;
    size_t rowbase = dir ? ((size_t)MFWD + (size_t)b * TBWD) : ((size_t)b * NTOK);
    const float* dS = dir ? dSB : dSF;
    const float* Dcs = dir ? DcsB : DcsF;
    const __bf16* Chat = dir ? ChatB : ChatF;
    int cmin = (layer == 1 && !dir) ? 6 : 1;
    int tid = threadIdx.x;
    __shared__ __bf16 Spl[8][64][40];
    {
        int p = tid >> 2, n0 = (tid & 3) * 8;
        float S[8];
        #pragma unroll
        for (int j = 0; j < 8; j++) S[j] = 0.f;
        for (int c = 0; c < NC; c++) {
            union { uint4 u; __bf16 hh[8]; } o;
            #pragma unroll
            for (int j = 0; j < 8; j++) o.hh[j] = (__bf16)S[j];
            *(uint4*)&Spl[c][p][n0] = o.u;
            float Dc = Dcs[bh * NC + c];
            const float4* dp = (const float4*)(dS + ((size_t)(bh * NC + c)) * 2048 + tid * 8);
            float4 d0 = dp[0], d1 = dp[1];
            S[0] = Dc * S[0] + d0.x; S[1] = Dc * S[1] + d0.y;
            S[2] = Dc * S[2] + d0.z; S[3] = Dc * S[3] + d0.w;
            S[4] = Dc * S[4] + d1.x; S[5] = Dc * S[5] + d1.y;
            S[6] = Dc * S[6] + d1.z; S[7] = Dc * S[7] + d1.w;
        }
    }
    __syncthreads();
    int w = tid >> 6, l = tid & 63, lm = l & 15, q = l >> 4;
    for (int c = cmin + w; c < NC; c += 4) {
        int t0 = c * 64;
        const __bf16* Cb = Chat + (size_t)(bh * NC + c) * 2048;
        bf16x8 cf[4], sf[4];
        #pragma unroll
        for (int t4 = 0; t4 < 4; t4++) {
            cf[t4] = *(const bf16x8*)(Cb + (t4 * 16 + lm) * 32 + q * 8);
            sf[t4] = *(const bf16x8*)&Spl[c][t4 * 16 + lm][q * 8];
        }
        #pragma unroll
        for (int ti = 0; ti < 4; ti++) {
            #pragma unroll
            for (int tp = 0; tp < 4; tp++) {
                f32x4 y = __builtin_amdgcn_mfma_f32_16x16x32_bf16(cf[ti], sf[tp], (f32x4)0.f, 0, 0, 0);
                #pragma unroll
                for (int r = 0; r < 4; r++) {
                    int i = ti * 16 + q * 4 + r;
                    size_t idx = (rowbase + t0 + i) * DINNER + hd * 64 + tp * 16 + lm;
                    ysD[idx] = (__bf16)((float)ysD[idx] + y[r]);
                }
            }
        }
    }
}

// ---------------- launch ----------------
extern "C" void kernel_launch(void* const* d_in, const int* in_sizes, int n_in,
                              void* d_out, int out_size, void* d_ws, size_t ws_size,
                              hipStream_t stream) {
    const float* x_prefix    = (const float*)d_in[0];
    const float* y_aux       = (const float*)d_in[1];
    const float* pre_conv_w  = (const float*)d_in[2];
    const float* pre_conv_b  = (const float*)d_in[3];
    const float* patch_w     = (const float*)d_in[4];
    const float* patch_b     = (const float*)d_in[5];
    const float* mask_token  = (const float*)d_in[6];
    const float* aux_w       = (const float*)d_in[7];
    const float* aux_b       = (const float*)d_in[8];
    const float* patch_out_w = (const float*)d_in[9];
    const float* patch_out_b = (const float*)d_in[10];
    const float* w_norm[2]   = {(const float*)d_in[11], (const float*)d_in[20]};
    const float* w_inproj[2] = {(const float*)d_in[12], (const float*)d_in[21]};
    const float* w_convw[2]  = {(const float*)d_in[13], (const float*)d_in[22]};
    const float* w_convb[2]  = {(const float*)d_in[14], (const float*)d_in[23]};
    const float* w_dtb[2]    = {(const float*)d_in[15], (const float*)d_in[24]};
    const float* w_alog[2]   = {(const float*)d_in[16], (const float*)d_in[25]};
    const float* w_D[2]      = {(const float*)d_in[17], (const float*)d_in[26]};
    const float* w_gnorm[2]  = {(const float*)d_in[18], (const float*)d_in[27]};
    const float* w_outproj[2]= {(const float*)d_in[19], (const float*)d_in[28]};

    char* p = (char*)d_ws;
    auto alloc = [&](size_t bytes) { char* r = p; p += (bytes + 255) & ~255ULL; return r; };
    __bf16* A_patch  = (__bf16*)alloc((size_t)3072 * 4096 * 2);
    __bf16* WpreT    = (__bf16*)alloc((size_t)256 * 64 * 2);
    __bf16* WtT      = (__bf16*)alloc((size_t)256 * 4096 * 2);
    __bf16* inprojT  = (__bf16*)alloc((size_t)4 * 1152 * 256 * 2);
    __bf16* outprojT = (__bf16*)alloc((size_t)4 * 256 * 512 * 2);
    __bf16* poT      = (__bf16*)alloc((size_t)128 * 512 * 2);
    float*  h_all    = (float*)alloc((size_t)MALL * 256 * 4);
    __bf16* zxb      = (__bf16*)alloc((size_t)MALL * ZXW * 2);
    float*  dtc      = (float*)alloc((size_t)MALL * 8 * 4);
    __bf16* ysD      = (__bf16*)alloc((size_t)MALL * DINNER * 2);
    __bf16* ChatF    = (__bf16*)alloc((size_t)64 * 8 * 2048 * 2);
    __bf16* ChatB    = (__bf16*)alloc((size_t)64 * 2 * 2048 * 2);
    float*  dSF      = (float*)alloc((size_t)64 * 8 * 2048 * 4);
    float*  dSB      = (float*)alloc((size_t)64 * 2 * 2048 * 4);
    float*  DcsF     = (float*)alloc((size_t)64 * 8 * 4);
    float*  DcsB     = (float*)alloc((size_t)64 * 2 * 4);

    // 1) prep: weights + d_out bias + h_all background (bias/mask + aux)
    prep_all<<<256 + 1152 + 512 + 64 + 64 + 512 + MALL, 256, 0, stream>>>(
        pre_conv_w, patch_w, w_inproj[0], w_inproj[1], w_outproj[0], w_outproj[1],
        patch_out_w, patch_out_b, y_aux, aux_w, aux_b, patch_b, mask_token,
        WpreT, WtT, inprojT, outprojT, poT, (float*)d_out, h_all);
    // 2) pre-conv GEMM with fused im2row (silu+bf16 -> A_patch)
    preconv_gemm<<<dim3(2, (BSZ * TPREF) / 128), 256, 0, stream>>>(
        x_prefix, WpreT, pre_conv_b, A_patch);
    // 3) patch GEMM: split-K 8, atomicAdd into pre-initialized h_all (row remap)
    gemm_mfma<<<dim3(2, 24, 8), 256, 0, stream>>>(
        A_patch, WtT, h_all, nullptr, 256, 4096, 256, 16);

    for (int i = 0; i < 2; i++) {
        const __bf16* ipTf = inprojT + (size_t)(0 * 2 + i) * 1152 * 256;
        const __bf16* ipTb = inprojT + (size_t)(1 * 2 + i) * 1152 * 256;
        const __bf16* opTf = outprojT + (size_t)(0 * 2 + i) * 256 * 512;
        const __bf16* opTb = outprojT + (size_t)(1 * 2 + i) * 256 * 512;
        // inproj with fused rmsnorm (reads fp32 h_all directly)
        gemm_inproj<<<dim3(9, MALL / 128), 256, 0, stream>>>(
            h_all, w_norm[0] + i * 256, w_norm[1] + i * 256, ipTf, ipTb, zxb, dtc);
        scan_local<<<dim3(80, NHEADS), 256, 0, stream>>>(
            zxb,
            w_convw[0] + i * CONVDIM * 4, w_convb[0] + i * CONVDIM,
            w_convw[1] + i * CONVDIM * 4, w_convb[1] + i * CONVDIM,
            dtc,
            w_dtb[0] + i * 8, w_dtb[1] + i * 8,
            w_alog[0] + i * 8, w_alog[1] + i * 8,
            w_D[0] + i * 8, w_D[1] + i * 8,
            ysD, ChatF, ChatB, dSF, dSB, DcsF, DcsB, i);
        scan_tail<<<128, 256, 0, stream>>>(dSF, dSB, DcsF, DcsB, ChatF, ChatB, ysD, i);
        // outproj with fused gatednorm (reads ysD + zxb directly)
        int oy = (i == 0) ? (MALL / 128) : 16;
        gemm_outproj<<<dim3(2, oy), 256, 0, stream>>>(
            ysD, zxb, w_gnorm[0] + i * DINNER, w_gnorm[1] + i * DINNER,
            opTf, opTb, h_all, i);
    }

    // final: fused hcat gather + patch_out GEMM, split-K 4, atomic into bias-initialized d_out
    final_gemm<<<dim3(1, 8, 4), 256, 0, stream>>>(h_all, poT, (float*)d_out);
}

// Round 7
// 322.182 us; speedup vs baseline: 1.1324x; 1.1324x over previous
//
#include <hip/hip_runtime.h>
#include <hip/hip_bf16.h>
#include <math.h>

// ---------------- constants ----------------
#define BSZ      8
#define TPREF    6144
#define CIN      8
#define DMODEL   256
#define DINNER   512
#define DSTATE   32
#define NHEADS   8
#define HEADDIM  64
#define CONVDIM  576
#define DPROJ    1096
#define ZXW      1088              // bf16 zx width (z 0..511 | xBC 512..1087)
#define NTOK     512
#define NVIS     384
#define TBWD     128
#define MFWD     (BSZ * NTOK)      // 4096 rows
#define MBWD     (BSZ * TBWD)      // 1024 rows
#define MALL     (MFWD + MBWD)     // 5120 rows

typedef float f32x4 __attribute__((ext_vector_type(4)));
typedef __bf16 bf16x8 __attribute__((ext_vector_type(8)));

__device__ __forceinline__ float silu_f(float x) { return x / (1.f + expf(-x)); }

#define ASYNC16(gp, lp) \
    __builtin_amdgcn_global_load_lds((const __attribute__((address_space(1))) void*)(gp), \
                                     (__attribute__((address_space(3))) void*)(lp), 16, 0, 0)

// ---------------- generic bf16 MFMA GEMM (NT): C[m,n] = sum_k A[m,k]*Bt[n,k] ----------------
// flags: 2=atomicAdd; 4=silu(v+bias)+bf16 store; 16=atomicAdd into h_all with (b,tok)->row remap
__global__ __launch_bounds__(256) void gemm_mfma(
    const __bf16* __restrict__ A, const __bf16* __restrict__ Bt,
    float* __restrict__ C, const float* __restrict__ bias,
    int N, int K, int ldc, int flags) {
    __shared__ char sm[16384];
    int tid = threadIdx.x;
    int m0 = blockIdx.y * 128, n0 = blockIdx.x * 128;
    int klen = K / gridDim.z;
    int kbeg = blockIdx.z * klen;
    int w = tid >> 6, l = tid & 63;
    int wm = w >> 1, wn = w & 1;
    int lm = l & 15, q = l >> 4;

    f32x4 acc[4][4];
    #pragma unroll
    for (int i = 0; i < 4; i++)
        #pragma unroll
        for (int j = 0; j < 4; j++) acc[i][j] = (f32x4)0.f;

    for (int k0 = 0; k0 < klen; k0 += 32) {
        int kb = kbeg + k0;
        #pragma unroll
        for (int i = 0; i < 2; i++) {
            int s = i * 256 + tid;
            ASYNC16(A + (size_t)(m0 + (s >> 2)) * K + kb + (s & 3) * 8, sm + s * 16);
        }
        #pragma unroll
        for (int i = 0; i < 2; i++) {
            int s = i * 256 + tid;
            ASYNC16(Bt + (size_t)(n0 + (s >> 2)) * K + kb + (s & 3) * 8, sm + 8192 + s * 16);
        }
        __syncthreads();
        bf16x8 af[4], bfr[4];
        #pragma unroll
        for (int mf = 0; mf < 4; mf++)
            af[mf] = *(const bf16x8*)(sm + (wm * 64 + mf * 16 + lm) * 64 + q * 16);
        #pragma unroll
        for (int nf = 0; nf < 4; nf++)
            bfr[nf] = *(const bf16x8*)(sm + 8192 + (wn * 64 + nf * 16 + lm) * 64 + q * 16);
        #pragma unroll
        for (int mf = 0; mf < 4; mf++)
            #pragma unroll
            for (int nf = 0; nf < 4; nf++)
                acc[mf][nf] = __builtin_amdgcn_mfma_f32_16x16x32_bf16(af[mf], bfr[nf], acc[mf][nf], 0, 0, 0);
        __syncthreads();
    }

    #pragma unroll
    for (int mf = 0; mf < 4; mf++) {
        int mbase = m0 + wm * 64 + mf * 16 + q * 4;
        #pragma unroll
        for (int nf = 0; nf < 4; nf++) {
            int n = n0 + wn * 64 + nf * 16 + lm;
            if (n < N) {
                #pragma unroll
                for (int r = 0; r < 4; r++) {
                    float v = acc[mf][nf][r];
                    if (flags & 4) {
                        v = silu_f(v + bias[n]);
                        ((__bf16*)C)[(size_t)(mbase + r) * ldc + n] = (__bf16)v;
                    } else if (flags & 16) {
                        int mm = mbase + r;
                        int bb = mm / NVIS, tk = mm - bb * NVIS;   // m = b*384+tok
                        atomicAdd(C + ((size_t)(bb * NTOK + tk)) * 256 + n, v);
                    } else if (flags & 2) {
                        atomicAdd(C + (size_t)(mbase + r) * ldc + n, v);
                    } else {
                        C[(size_t)(mbase + r) * ldc + n] = v;
                    }
                }
            }
        }
    }
}

// ---------------- pre-conv GEMM with fused im2row ----------------
__global__ __launch_bounds__(256) void preconv_gemm(
    const float* __restrict__ xp, const __bf16* __restrict__ WpreT,
    const float* __restrict__ bias, __bf16* __restrict__ Apatch) {
    __shared__ char sm[32768];   // A: [2][128][32]bf16 = 16KB @0, B: same @16384
    int tid = threadIdx.x;
    int m0 = blockIdx.y * 128, n0 = blockIdx.x * 128;
    int w = tid >> 6, l = tid & 63;
    int wm = w >> 1, wn = w & 1, lm = l & 15, q = l >> 4;

    #pragma unroll
    for (int i = 0; i < 4; i++) {
        int s = i * 256 + tid;
        int kh = s >> 9, row = (s & 511) >> 2, within = s & 3;
        ASYNC16(WpreT + (size_t)(n0 + row) * 64 + kh * 32 + within * 8, sm + 16384 + s * 16);
    }
    if (tid < 128) {
        int m = m0 + tid;
        int b = m / TPREF, t = m - b * TPREF;
        __bf16 d[64];
        #pragma unroll
        for (int j = 40; j < 64; j++) d[j] = (__bf16)0.f;
        #pragma unroll
        for (int k = 0; k < 5; k++) {
            int tt = t - 2 + k;
            bool ok = (tt >= 0) && (tt < TPREF);
            const float* s = xp + ((size_t)b * TPREF + tt) * 8;
            #pragma unroll
            for (int i = 0; i < 8; i++)
                d[i * 5 + k] = ok ? (__bf16)s[i] : (__bf16)0.f;
        }
        uint4* o0 = (uint4*)(sm + tid * 64);
        uint4* o1 = (uint4*)(sm + 8192 + tid * 64);
        #pragma unroll
        for (int k = 0; k < 4; k++) { o0[k] = ((const uint4*)d)[k]; o1[k] = ((const uint4*)d)[4 + k]; }
    }
    __syncthreads();

    f32x4 acc[4][4];
    #pragma unroll
    for (int i = 0; i < 4; i++)
        #pragma unroll
        for (int j = 0; j < 4; j++) acc[i][j] = (f32x4)0.f;
    #pragma unroll
    for (int kh = 0; kh < 2; kh++) {
        bf16x8 af[4], bfr[4];
        #pragma unroll
        for (int mf = 0; mf < 4; mf++)
            af[mf] = *(const bf16x8*)(sm + kh * 8192 + (wm * 64 + mf * 16 + lm) * 64 + q * 16);
        #pragma unroll
        for (int nf = 0; nf < 4; nf++)
            bfr[nf] = *(const bf16x8*)(sm + 16384 + kh * 8192 + (wn * 64 + nf * 16 + lm) * 64 + q * 16);
        #pragma unroll
        for (int mf = 0; mf < 4; mf++)
            #pragma unroll
            for (int nf = 0; nf < 4; nf++)
                acc[mf][nf] = __builtin_amdgcn_mfma_f32_16x16x32_bf16(af[mf], bfr[nf], acc[mf][nf], 0, 0, 0);
    }
    #pragma unroll
    for (int mf = 0; mf < 4; mf++) {
        int mbase = m0 + wm * 64 + mf * 16 + q * 4;
        #pragma unroll
        for (int nf = 0; nf < 4; nf++) {
            int n = n0 + wn * 64 + nf * 16 + lm;
            #pragma unroll
            for (int r = 0; r < 4; r++) {
                float v = silu_f(acc[mf][nf][r] + bias[n]);
                Apatch[(size_t)(mbase + r) * 256 + n] = (__bf16)v;
            }
        }
    }
}

// ---------------- final GEMM: hcat gather fused; split-K 4 (dir x k-half) ----------------
__global__ __launch_bounds__(256) void final_gemm(
    const float* __restrict__ h_all, const __bf16* __restrict__ poT,
    float* __restrict__ out) {
    __shared__ __bf16 Asm_[128][40];
    __shared__ char Bsm[8192];
    int tid = threadIdx.x;
    int m0 = blockIdx.y * 128;
    int z = blockIdx.z;                 // 0..3
    int dir = z >> 1, kh = z & 1;
    int koff = kh * 128;
    int w = tid >> 6, l = tid & 63;
    int wm = w >> 1, wn_ = w & 1, lm = l & 15, q = l >> 4;
    f32x4 acc[4][4];
    #pragma unroll
    for (int i = 0; i < 4; i++)
        #pragma unroll
        for (int j = 0; j < 4; j++) acc[i][j] = (f32x4)0.f;

    int r = tid >> 1, half = tid & 1;
    int m = m0 + r;
    int b = m >> 7, jj = m & 127;
    size_t arow = (dir == 0) ? ((size_t)(b * NTOK + NVIS + jj) * 256)
                             : ((size_t)MFWD * 256 + (size_t)(b * TBWD + (TBWD - 1 - jj)) * 256);
    for (int k0 = 0; k0 < 128; k0 += 32) {
        {
            const float4* sp = (const float4*)(h_all + arow + koff + k0 + half * 16);
            float4 v0 = sp[0], v1 = sp[1], v2 = sp[2], v3 = sp[3];
            union { uint4 u; __bf16 hh[8]; } d0, d1;
            d0.hh[0] = (__bf16)v0.x; d0.hh[1] = (__bf16)v0.y; d0.hh[2] = (__bf16)v0.z; d0.hh[3] = (__bf16)v0.w;
            d0.hh[4] = (__bf16)v1.x; d0.hh[5] = (__bf16)v1.y; d0.hh[6] = (__bf16)v1.z; d0.hh[7] = (__bf16)v1.w;
            d1.hh[0] = (__bf16)v2.x; d1.hh[1] = (__bf16)v2.y; d1.hh[2] = (__bf16)v2.z; d1.hh[3] = (__bf16)v2.w;
            d1.hh[4] = (__bf16)v3.x; d1.hh[5] = (__bf16)v3.y; d1.hh[6] = (__bf16)v3.z; d1.hh[7] = (__bf16)v3.w;
            *(uint4*)&Asm_[r][half * 16] = d0.u;
            *(uint4*)&Asm_[r][half * 16 + 8] = d1.u;
        }
        #pragma unroll
        for (int i = 0; i < 2; i++) {
            int s = i * 256 + tid;
            ASYNC16(poT + (size_t)(s >> 2) * 512 + dir * 256 + koff + k0 + (s & 3) * 8, Bsm + s * 16);
        }
        __syncthreads();
        bf16x8 af[4], bfr[4];
        #pragma unroll
        for (int mf = 0; mf < 4; mf++)
            af[mf] = *(const bf16x8*)&Asm_[wm * 64 + mf * 16 + lm][q * 8];
        #pragma unroll
        for (int nf = 0; nf < 4; nf++)
            bfr[nf] = *(const bf16x8*)(Bsm + (wn_ * 64 + nf * 16 + lm) * 64 + q * 16);
        #pragma unroll
        for (int mf = 0; mf < 4; mf++)
            #pragma unroll
            for (int nf = 0; nf < 4; nf++)
                acc[mf][nf] = __builtin_amdgcn_mfma_f32_16x16x32_bf16(af[mf], bfr[nf], acc[mf][nf], 0, 0, 0);
        __syncthreads();
    }
    #pragma unroll
    for (int mf = 0; mf < 4; mf++) {
        int mbase = m0 + wm * 64 + mf * 16 + q * 4;
        #pragma unroll
        for (int nf = 0; nf < 4; nf++) {
            int n = wn_ * 64 + nf * 16 + lm;
            #pragma unroll
            for (int rr = 0; rr < 4; rr++)
                atomicAdd(out + (size_t)(mbase + rr) * 128 + n, acc[mf][nf][rr]);
        }
    }
}

// ---------------- inproj GEMM: 128x128 tile, K=256; bf16 zxb + fp32 dtc outputs ----------------
__global__ __launch_bounds__(256) void gemm_inproj(
    const __bf16* __restrict__ u, const __bf16* __restrict__ ipTf,
    const __bf16* __restrict__ ipTb, __bf16* __restrict__ zxb, float* __restrict__ dtc) {
    __shared__ char sm[16384];
    int tid = threadIdx.x;
    int m0 = blockIdx.y * 128, n0 = blockIdx.x * 128;
    const __bf16* Bt = (m0 >= MFWD) ? ipTb : ipTf;
    int w = tid >> 6, l = tid & 63;
    int wm = w >> 1, wn = w & 1, lm = l & 15, q = l >> 4;
    f32x4 acc[4][4];
    #pragma unroll
    for (int i = 0; i < 4; i++)
        #pragma unroll
        for (int j = 0; j < 4; j++) acc[i][j] = (f32x4)0.f;
    for (int k0 = 0; k0 < 256; k0 += 32) {
        #pragma unroll
        for (int i = 0; i < 2; i++) {
            int s = i * 256 + tid;
            ASYNC16(u + (size_t)(m0 + (s >> 2)) * 256 + k0 + (s & 3) * 8, sm + s * 16);
        }
        #pragma unroll
        for (int i = 0; i < 2; i++) {
            int s = i * 256 + tid;
            ASYNC16(Bt + (size_t)(n0 + (s >> 2)) * 256 + k0 + (s & 3) * 8, sm + 8192 + s * 16);
        }
        __syncthreads();
        bf16x8 af[4], bfr[4];
        #pragma unroll
        for (int mf = 0; mf < 4; mf++)
            af[mf] = *(const bf16x8*)(sm + (wm * 64 + mf * 16 + lm) * 64 + q * 16);
        #pragma unroll
        for (int nf = 0; nf < 4; nf++)
            bfr[nf] = *(const bf16x8*)(sm + 8192 + (wn * 64 + nf * 16 + lm) * 64 + q * 16);
        #pragma unroll
        for (int mf = 0; mf < 4; mf++)
            #pragma unroll
            for (int nf = 0; nf < 4; nf++)
                acc[mf][nf] = __builtin_amdgcn_mfma_f32_16x16x32_bf16(af[mf], bfr[nf], acc[mf][nf], 0, 0, 0);
        __syncthreads();
    }
    #pragma unroll
    for (int mf = 0; mf < 4; mf++) {
        int mbase = m0 + wm * 64 + mf * 16 + q * 4;
        #pragma unroll
        for (int nf = 0; nf < 4; nf++) {
            int n = n0 + wn * 64 + nf * 16 + lm;
            #pragma unroll
            for (int r = 0; r < 4; r++) {
                float v = acc[mf][nf][r];
                if (n < ZXW) zxb[(size_t)(mbase + r) * ZXW + n] = (__bf16)v;
                else if (n < DPROJ) dtc[(size_t)(mbase + r) * 8 + (n - ZXW)] = v;
            }
        }
    }
}

// ---------------- outproj GEMM: 128x128 tile, K=512, layer-aware rows, residual += ----------------
__global__ __launch_bounds__(256) void gemm_outproj(
    const __bf16* __restrict__ y2, const __bf16* __restrict__ opTf,
    const __bf16* __restrict__ opTb, float* __restrict__ C, int layer) {
    __shared__ char sm[16384];
    int tid = threadIdx.x;
    int yb = blockIdx.y;
    int m0 = (layer == 0) ? yb * 128
                          : ((yb < 8) ? (yb * 512 + 384) : (MFWD + (yb - 8) * 128));
    int n0 = blockIdx.x * 128;
    const __bf16* Bt = (m0 >= MFWD) ? opTb : opTf;
    int w = tid >> 6, l = tid & 63;
    int wm = w >> 1, wn = w & 1, lm = l & 15, q = l >> 4;
    f32x4 acc[4][4];
    #pragma unroll
    for (int i = 0; i < 4; i++)
        #pragma unroll
        for (int j = 0; j < 4; j++) acc[i][j] = (f32x4)0.f;
    for (int k0 = 0; k0 < 512; k0 += 32) {
        #pragma unroll
        for (int i = 0; i < 2; i++) {
            int s = i * 256 + tid;
            ASYNC16(y2 + (size_t)(m0 + (s >> 2)) * 512 + k0 + (s & 3) * 8, sm + s * 16);
        }
        #pragma unroll
        for (int i = 0; i < 2; i++) {
            int s = i * 256 + tid;
            ASYNC16(Bt + (size_t)(n0 + (s >> 2)) * 512 + k0 + (s & 3) * 8, sm + 8192 + s * 16);
        }
        __syncthreads();
        bf16x8 af[4], bfr[4];
        #pragma unroll
        for (int mf = 0; mf < 4; mf++)
            af[mf] = *(const bf16x8*)(sm + (wm * 64 + mf * 16 + lm) * 64 + q * 16);
        #pragma unroll
        for (int nf = 0; nf < 4; nf++)
            bfr[nf] = *(const bf16x8*)(sm + 8192 + (wn * 64 + nf * 16 + lm) * 64 + q * 16);
        #pragma unroll
        for (int mf = 0; mf < 4; mf++)
            #pragma unroll
            for (int nf = 0; nf < 4; nf++)
                acc[mf][nf] = __builtin_amdgcn_mfma_f32_16x16x32_bf16(af[mf], bfr[nf], acc[mf][nf], 0, 0, 0);
        __syncthreads();
    }
    #pragma unroll
    for (int mf = 0; mf < 4; mf++) {
        int mbase = m0 + wm * 64 + mf * 16 + q * 4;
        #pragma unroll
        for (int nf = 0; nf < 4; nf++) {
            int n = n0 + wn * 64 + nf * 16 + lm;
            #pragma unroll
            for (int r = 0; r < 4; r++) {
                size_t ci = (size_t)(mbase + r) * DMODEL + n;
                C[ci] += acc[mf][nf][r];
            }
        }
    }
}

// ---------------- elementwise norms ----------------
__global__ __launch_bounds__(256) void rmsnorm_all(
    const float* __restrict__ h, const float* __restrict__ wf,
    const float* __restrict__ wb, __bf16* __restrict__ u) {
    int row = blockIdx.x * 4 + (threadIdx.x >> 6);
    int lane = threadIdx.x & 63;
    const float* w = (row >= MFWD) ? wb : wf;
    float4 v = ((const float4*)(h + (size_t)row * 256))[lane];
    float ss = v.x * v.x + v.y * v.y + v.z * v.z + v.w * v.w;
    #pragma unroll
    for (int off = 32; off >= 1; off >>= 1) ss += __shfl_xor(ss, off);
    float rs = rsqrtf(ss * (1.f / 256.f) + 1e-5f);
    float4 wv = ((const float4*)w)[lane];
    __bf16 o4[4] = {(__bf16)(v.x * rs * wv.x), (__bf16)(v.y * rs * wv.y),
                    (__bf16)(v.z * rs * wv.z), (__bf16)(v.w * rs * wv.w)};
    *(uint2*)(u + (size_t)row * 256 + lane * 4) = *(uint2*)o4;
}

// gatednorm: layer 0 covers all rows (grid 1280); layer 1 covers only the 2048
// rows consumed by outproj layer 1 (grid 512): fwd rows b*512+384..511, all bwd rows.
__global__ __launch_bounds__(256) void gatednorm_all(
    const __bf16* __restrict__ ysD, const __bf16* __restrict__ zxb,
    const float* __restrict__ gwf, const float* __restrict__ gwb,
    __bf16* __restrict__ y2, int layer) {
    int blk = blockIdx.x;
    int sub = threadIdx.x >> 6;
    int row;
    if (layer == 0) {
        row = blk * 4 + sub;
    } else {
        if (blk < 256) { int b = blk >> 5; row = b * 512 + 384 + (blk & 31) * 4 + sub; }
        else           { row = MFWD + (blk - 256) * 4 + sub; }
    }
    int lane = threadIdx.x & 63;
    const float* gw = (row >= MFWD) ? gwb : gwf;
    union { uint4 u; __bf16 hh[8]; } yv, zv;
    yv.u = *(const uint4*)(ysD + (size_t)row * 512 + lane * 8);
    zv.u = *(const uint4*)(zxb + (size_t)row * ZXW + lane * 8);
    float g[8];
    #pragma unroll
    for (int j = 0; j < 8; j++) g[j] = (float)yv.hh[j] * silu_f((float)zv.hh[j]);
    float ss = 0.f;
    #pragma unroll
    for (int j = 0; j < 8; j++) ss += g[j] * g[j];
    #pragma unroll
    for (int off = 32; off >= 1; off >>= 1) ss += __shfl_xor(ss, off);
    float rs = rsqrtf(ss * (1.f / 512.f) + 1e-5f);
    const float4* gr = (const float4*)(gw + lane * 8);
    float4 g0 = gr[0], g1 = gr[1];
    union { uint4 u; __bf16 hh[8]; } d;
    d.hh[0] = (__bf16)(g[0] * rs * g0.x); d.hh[1] = (__bf16)(g[1] * rs * g0.y);
    d.hh[2] = (__bf16)(g[2] * rs * g0.z); d.hh[3] = (__bf16)(g[3] * rs * g0.w);
    d.hh[4] = (__bf16)(g[4] * rs * g1.x); d.hh[5] = (__bf16)(g[5] * rs * g1.y);
    d.hh[6] = (__bf16)(g[6] * rs * g1.z); d.hh[7] = (__bf16)(g[7] * rs * g1.w);
    *(uint4*)(y2 + (size_t)row * 512 + lane * 8) = d.u;
}

// ---------------- segmented prep kernel (all coalesced) ----------------
// WtT 256 | inprojT 1152 | outprojT 512 | poT 64 | WpreT 64 | dout 512 | hinit 5120
__global__ void prep_all(const float* __restrict__ pre_conv_w, const float* __restrict__ patch_w,
                         const float* __restrict__ ip0, const float* __restrict__ ip1,
                         const float* __restrict__ op0, const float* __restrict__ op1,
                         const float* __restrict__ pow_, const float* __restrict__ pob,
                         const float* __restrict__ y_aux, const float* __restrict__ aux_w,
                         const float* __restrict__ aux_b,
                         const float* __restrict__ patch_b, const float* __restrict__ mtok,
                         __bf16* __restrict__ WpreT, __bf16* __restrict__ WtT,
                         __bf16* __restrict__ inprojT, __bf16* __restrict__ outprojT,
                         __bf16* __restrict__ poT, float* __restrict__ dout,
                         float* __restrict__ h_all) {
    __shared__ float tile[32][33];
    int bx = blockIdx.x, tid = threadIdx.x;
    int tx = tid & 31, ty = tid >> 5;
    if (bx < 256) {
        int o = bx, c = tid;
        float f[16];
        const float4* s = (const float4*)(patch_w + (size_t)o * 4096 + c * 16);
        #pragma unroll
        for (int j = 0; j < 4; j++) *(float4*)&f[j * 4] = s[j];
        #pragma unroll
        for (int k = 0; k < 16; k++)
            WtT[(size_t)o * 4096 + k * 256 + c] = (__bf16)f[k];
        return;
    }
    bx -= 256;
    if (bx < 1152) {
        int seg = bx / 288, rem = bx % 288;
        int n0 = (rem / 8) * 32, k0 = (rem % 8) * 32;
        const float* src = (seg < 2 ? ip0 : ip1) + (size_t)(seg & 1) * 256 * DPROJ;
        #pragma unroll
        for (int j = 0; j < 4; j++) {
            int r = ty + j * 8;
            int n = n0 + tx;
            tile[r][tx] = (n < DPROJ) ? src[(size_t)(k0 + r) * DPROJ + n] : 0.f;
        }
        __syncthreads();
        __bf16* dst = inprojT + (size_t)seg * 1152 * 256;
        #pragma unroll
        for (int j = 0; j < 4; j++) {
            int r = ty + j * 8;
            dst[(size_t)(n0 + r) * 256 + k0 + tx] = (__bf16)tile[tx][r];
        }
        return;
    }
    bx -= 1152;
    if (bx < 512) {
        int s = bx / 128, rem = bx % 128;
        int n0 = (rem / 16) * 32, k0 = (rem % 16) * 32;
        const float* src = (s < 2 ? op0 : op1) + (size_t)(s & 1) * DINNER * DMODEL;
        #pragma unroll
        for (int j = 0; j < 4; j++) {
            int r = ty + j * 8;
            tile[r][tx] = src[(size_t)(k0 + r) * 256 + n0 + tx];
        }
        __syncthreads();
        __bf16* dst = outprojT + (size_t)s * 256 * 512;
        #pragma unroll
        for (int j = 0; j < 4; j++) {
            int r = ty + j * 8;
            dst[(size_t)(n0 + r) * 512 + k0 + tx] = (__bf16)tile[tx][r];
        }
        return;
    }
    bx -= 512;
    if (bx < 64) {
        int n0 = (bx / 16) * 32, k0 = (bx % 16) * 32;
        #pragma unroll
        for (int j = 0; j < 4; j++) {
            int r = ty + j * 8;
            tile[r][tx] = pow_[(size_t)(k0 + r) * 128 + n0 + tx];
        }
        __syncthreads();
        #pragma unroll
        for (int j = 0; j < 4; j++) {
            int r = ty + j * 8;
            poT[(size_t)(n0 + r) * 512 + k0 + tx] = (__bf16)tile[tx][r];
        }
        return;
    }
    bx -= 64;
    if (bx < 64) {
        int idx = bx * 256 + tid;
        int o = idx >> 6, kk = idx & 63;
        WpreT[idx] = (kk < 40) ? (__bf16)pre_conv_w[o * 40 + kk] : (__bf16)0.f;
        return;
    }
    bx -= 64;
    if (bx < 512) {
        int idx = bx * 256 + tid;
        dout[idx] = pob[idx & 127];
        return;
    }
    bx -= 512;
    {   // h_all init: visible fwd rows = patch_b+aux (GEMM atomically adds patch term);
        // masked fwd rows and all bwd rows = mask_token+aux
        int row = bx, o = tid;
        int b; bool masked;
        if (row < MFWD) { b = row >> 9; int tok = row & 511; masked = (tok >= NVIS); }
        else { b = (row - MFWD) >> 7; masked = true; }
        float acc = aux_b[o];
        #pragma unroll
        for (int i = 0; i < 16; i++) acc += y_aux[b * 16 + i] * aux_w[i * 256 + o];
        float v = (masked ? mtok[o] : patch_b[o]) + silu_f(acc);
        h_all[(size_t)row * 256 + o] = v;
    }
}

// ---------------- chunked SSD scan phase A with fused depthwise conv: 4 waves/block ----------------
// grid (80, 8). Stages raw X/BC slices from zxb cooperatively (uint4), conv k=4 + silu in-block.
__global__ __launch_bounds__(256) void scan_local(
    const __bf16* __restrict__ zxb,
    const float* __restrict__ cwf, const float* __restrict__ cbf,
    const float* __restrict__ cwb, const float* __restrict__ cbb,
    const float* __restrict__ dtc,
    const float* __restrict__ dtbf, const float* __restrict__ dtbb,
    const float* __restrict__ Alogf, const float* __restrict__ Alogb,
    const float* __restrict__ Dpf, const float* __restrict__ Dpb,
    __bf16* __restrict__ ysD,
    __bf16* __restrict__ ChatF, __bf16* __restrict__ ChatB,
    float* __restrict__ dSF, float* __restrict__ dSB,
    float* __restrict__ DcsF, float* __restrict__ DcsB, int layer) {
    int id = blockIdx.x, hd = blockIdx.y;
    int b, c, T, NC; size_t rowbase;
    __bf16* Chat; float *dS, *Dcs;
    const float *dtb, *Alog, *Dp, *cw, *cb;
    if (id < 64) { b = id >> 3; c = id & 7; T = NTOK; NC = 8; rowbase = (size_t)b * NTOK;
                   Chat = ChatF; dS = dSF; Dcs = DcsF;
                   dtb = dtbf; Alog = Alogf; Dp = Dpf; cw = cwf; cb = cbf; }
    else { int i2 = id - 64; b = i2 >> 1; c = i2 & 1; T = TBWD; NC = 2;
           rowbase = (size_t)MFWD + (size_t)b * TBWD;
           Chat = ChatB; dS = dSB; Dcs = DcsB;
           dtb = dtbb; Alog = Alogb; Dp = Dpb; cw = cwb; cb = cbb; }
    bool skipY = (layer == 1) && (id < 64) && (c < 6);
    int bh = b * 8 + hd;
    int t0 = c * 64;
    int tid = threadIdx.x;
    int w = tid >> 6, l = tid & 63;
    int lm = l & 15, q = l >> 4;
    float A = -expf(Alog[hd]);
    float Dh = Dp[hd];

    __shared__ char smem[40704];
    __bf16 (*Xl)[72]  = (__bf16(*)[72])(smem);            // Xl[ch][t] post-conv
    __bf16 (*BCl)[72] = (__bf16(*)[72])(smem + 9216);     // BCl[t][ch] post-conv
    __bf16 (*Pl)[72]  = (__bf16(*)[72])(smem + 9216);     // overwrites BCl after reads done
    __bf16 (*Wbl)[72] = (__bf16(*)[72])(smem + 18432);
    float* lcs = (float*)(smem + 23040);
    float* dts = (float*)(smem + 23296);
    __bf16 (*xraw)[64] = (__bf16(*)[64])(smem + 23552);   // 67x64 raw X (this head)
    __bf16 (*braw)[64] = (__bf16(*)[64])(smem + 32128);   // 67x64 raw BC

    // ---- stage raw slices: 1072 uint4 chunks over 256 threads ----
    for (int s = tid; s < 1072; s += 256) {
        int arr = (s >= 536) ? 1 : 0;
        int s2 = s - arr * 536;
        int r = s2 >> 3, seg = s2 & 7;
        int t = t0 - 3 + r;
        uint4 v = make_uint4(0u, 0u, 0u, 0u);
        if (t >= 0) {
            size_t col = arr ? (size_t)(1024 + seg * 8) : (size_t)(DINNER + hd * 64 + seg * 8);
            v = *(const uint4*)(zxb + (rowbase + t) * (size_t)ZXW + col);
        }
        if (arr) *(uint4*)&braw[r][seg * 8] = v;
        else     *(uint4*)&xraw[r][seg * 8] = v;
    }
    __syncthreads();

    // ---- conv X: ch = lane, t-quarter = wave; pack 16 outputs -> Xl[ch][t] ----
    {
        int cX = hd * 64 + l;
        float w0 = cw[cX * 4], w1 = cw[cX * 4 + 1], w2 = cw[cX * 4 + 2], w3 = cw[cX * 4 + 3];
        float cbv = cb[cX];
        int tb = w * 16;
        float a0 = (float)xraw[tb][l], a1 = (float)xraw[tb + 1][l], a2 = (float)xraw[tb + 2][l];
        union { uint4 u; __bf16 h[8]; } p0, p1;
        #pragma unroll
        for (int j = 0; j < 16; j++) {
            float a3 = (float)xraw[tb + j + 3][l];
            float acc = cbv + w0 * a0 + w1 * a1 + w2 * a2 + w3 * a3;
            if (j < 8) p0.h[j] = (__bf16)silu_f(acc);
            else       p1.h[j - 8] = (__bf16)silu_f(acc);
            a0 = a1; a1 = a2; a2 = a3;
        }
        *(uint4*)&Xl[l][tb]     = p0.u;
        *(uint4*)&Xl[l][tb + 8] = p1.u;
    }
    // ---- conv BC: ch = lane, t-quarter = wave -> BCl[t][ch] (transposed, scalar stores) ----
    {
        int cc = 512 + l;
        float w0 = cw[cc * 4], w1 = cw[cc * 4 + 1], w2 = cw[cc * 4 + 2], w3 = cw[cc * 4 + 3];
        float cbv = cb[cc];
        int tb = w * 16;
        float a0 = (float)braw[tb][l], a1 = (float)braw[tb + 1][l], a2 = (float)braw[tb + 2][l];
        #pragma unroll
        for (int j = 0; j < 16; j++) {
            float a3 = (float)braw[tb + j + 3][l];
            float acc = cbv + w0 * a0 + w1 * a1 + w2 * a2 + w3 * a3;
            BCl[tb + j][l] = (__bf16)silu_f(acc);
            a0 = a1; a1 = a2; a2 = a3;
        }
    }
    // ---- per-token dt + cumulative log-decay (redundant per wave; lane = token) ----
    float xdt = dtc[(rowbase + t0 + l) * 8 + hd] + dtb[hd];
    float dtv = (xdt > 20.f) ? xdt : log1pf(expf(xdt));
    float lc = A * dtv;
    #pragma unroll
    for (int off = 1; off < 64; off <<= 1) {
        float o = __shfl_up(lc, off);
        if (l >= off) lc += o;
    }
    float lc63 = __shfl(lc, 63);
    float wj = expf(lc63 - lc) * dtv;
    float eli = expf(lc);
    if (w == 0) {
        lcs[l] = lc; dts[l] = dtv;
        if (l == 0) Dcs[bh * NC + c] = expf(lc63);
    }
    __syncthreads();   // conv outputs + lcs/dts visible

    // ---- Chat write (wave w: channel group w*8..w*8+7 of C part) ----
    if (!skipY) {
        union { uint4 u; __bf16 h[8]; } s, d;
        s.u = *(const uint4*)&BCl[l][32 + w * 8];
        #pragma unroll
        for (int j = 0; j < 8; j++) d.h[j] = (__bf16)(eli * (float)s.h[j]);
        *(uint4*)(Chat + ((size_t)(bh * NC + c) * 64 + l) * 32 + w * 8) = d.u;
    }
    // ---- Wbl[n][t] build (wave w: n group w*8..w*8+7) ----
    {
        union { uint4 u; __bf16 h[8]; } s;
        s.u = *(const uint4*)&BCl[l][w * 8];
        #pragma unroll
        for (int j = 0; j < 8; j++) Wbl[w * 8 + j][l] = (__bf16)(wj * (float)s.h[j]);
    }
    // ---- P-phase register loads (must complete before Pl overwrites BCl) ----
    bf16x8 cfr, bfr[4];
    if (!skipY) {
        cfr = *(const bf16x8*)&BCl[w * 16 + lm][32 + q * 8];
        #pragma unroll
        for (int tj = 0; tj < 4; tj++)
            if (tj <= w) bfr[tj] = *(const bf16x8*)&BCl[tj * 16 + lm][q * 8];
    }
    __syncthreads();   // all BCl reads done; Wbl complete

    if (!skipY) {
        float lci[4];
        #pragma unroll
        for (int r = 0; r < 4; r++) lci[r] = lcs[w * 16 + q * 4 + r];
        #pragma unroll
        for (int tj = 0; tj < 4; tj++) {
            if (tj > w) {
                #pragma unroll
                for (int r = 0; r < 4; r++) Pl[w * 16 + q * 4 + r][tj * 16 + lm] = (__bf16)0.f;
                continue;
            }
            f32x4 g = __builtin_amdgcn_mfma_f32_16x16x32_bf16(cfr, bfr[tj], (f32x4)0.f, 0, 0, 0);
            int j = tj * 16 + lm;
            float lcj = lcs[j], dtj = dts[j];
            #pragma unroll
            for (int r = 0; r < 4; r++) {
                int i = w * 16 + q * 4 + r;
                float v = (j <= i) ? g[r] * expf(lci[r] - lcj) * dtj : 0.f;
                if (j == i) v += Dh;
                Pl[i][j] = (__bf16)v;
            }
        }
    }
    __syncthreads();   // Pl ready

    bf16x8 xf0[4], xf1[4];
    #pragma unroll
    for (int t4 = 0; t4 < 4; t4++) {
        xf0[t4] = *(const bf16x8*)&Xl[t4 * 16 + lm][q * 8];
        xf1[t4] = *(const bf16x8*)&Xl[t4 * 16 + lm][32 + q * 8];
    }
    if (!skipY) {
        bf16x8 pf0 = *(const bf16x8*)&Pl[w * 16 + lm][q * 8];
        bf16x8 pf1 = *(const bf16x8*)&Pl[w * 16 + lm][32 + q * 8];
        #pragma unroll
        for (int tp = 0; tp < 4; tp++) {
            f32x4 y = __builtin_amdgcn_mfma_f32_16x16x32_bf16(pf0, xf0[tp], (f32x4)0.f, 0, 0, 0);
            y = __builtin_amdgcn_mfma_f32_16x16x32_bf16(pf1, xf1[tp], y, 0, 0, 0);
            #pragma unroll
            for (int r = 0; r < 4; r++) {
                int i = w * 16 + q * 4 + r;
                ysD[(rowbase + t0 + i) * DINNER + hd * 64 + tp * 16 + lm] = (__bf16)y[r];
            }
        }
    }
    // ---- dS (wave w = tp) ----
    bf16x8 wf0[2], wf1[2];
    #pragma unroll
    for (int tn = 0; tn < 2; tn++) {
        wf0[tn] = *(const bf16x8*)&Wbl[tn * 16 + lm][q * 8];
        wf1[tn] = *(const bf16x8*)&Wbl[tn * 16 + lm][32 + q * 8];
    }
    float* dso = dS + (size_t)(bh * NC + c) * 2048;
    #pragma unroll
    for (int tn = 0; tn < 2; tn++) {
        f32x4 s = __builtin_amdgcn_mfma_f32_16x16x32_bf16(xf0[w], wf0[tn], (f32x4)0.f, 0, 0, 0);
        s = __builtin_amdgcn_mfma_f32_16x16x32_bf16(xf1[w], wf1[tn], s, 0, 0, 0);
        #pragma unroll
        for (int r = 0; r < 4; r++) {
            int pp = w * 16 + q * 4 + r, nn = tn * 16 + lm;
            dso[pp * 32 + nn] = s[r];
        }
    }
}

// ---------------- scan tail: recurrence + cross-chunk Y add ----------------
__global__ __launch_bounds__(256) void scan_tail(
    const float* __restrict__ dSF, const float* __restrict__ dSB,
    const float* __restrict__ DcsF, const float* __restrict__ DcsB,
    const __bf16* __restrict__ ChatF, const __bf16* __restrict__ ChatB,
    __bf16* __restrict__ ysD, int layer) {
    int blk = blockIdx.x;
    int dir = blk >= 64;
    int bh = blk & 63;
    int NC = dir ? 2 : 8;
    int T = dir ? TBWD : NTOK;
    int b = bh >> 3, hd = bh & 7;
    size_t rowbase = dir ? ((size_t)MFWD + (size_t)b * TBWD) : ((size_t)b * NTOK);
    const float* dS = dir ? dSB : dSF;
    const float* Dcs = dir ? DcsB : DcsF;
    const __bf16* Chat = dir ? ChatB : ChatF;
    int cmin = (layer == 1 && !dir) ? 6 : 1;
    int tid = threadIdx.x;
    __shared__ __bf16 Spl[8][64][40];
    {
        int p = tid >> 2, n0 = (tid & 3) * 8;
        float S[8];
        #pragma unroll
        for (int j = 0; j < 8; j++) S[j] = 0.f;
        for (int c = 0; c < NC; c++) {
            union { uint4 u; __bf16 hh[8]; } o;
            #pragma unroll
            for (int j = 0; j < 8; j++) o.hh[j] = (__bf16)S[j];
            *(uint4*)&Spl[c][p][n0] = o.u;
            float Dc = Dcs[bh * NC + c];
            const float4* dp = (const float4*)(dS + ((size_t)(bh * NC + c)) * 2048 + tid * 8);
            float4 d0 = dp[0], d1 = dp[1];
            S[0] = Dc * S[0] + d0.x; S[1] = Dc * S[1] + d0.y;
            S[2] = Dc * S[2] + d0.z; S[3] = Dc * S[3] + d0.w;
            S[4] = Dc * S[4] + d1.x; S[5] = Dc * S[5] + d1.y;
            S[6] = Dc * S[6] + d1.z; S[7] = Dc * S[7] + d1.w;
        }
    }
    __syncthreads();
    int w = tid >> 6, l = tid & 63, lm = l & 15, q = l >> 4;
    for (int c = cmin + w; c < NC; c += 4) {
        int t0 = c * 64;
        const __bf16* Cb = Chat + (size_t)(bh * NC + c) * 2048;
        bf16x8 cf[4], sf[4];
        #pragma unroll
        for (int t4 = 0; t4 < 4; t4++) {
            cf[t4] = *(const bf16x8*)(Cb + (t4 * 16 + lm) * 32 + q * 8);
            sf[t4] = *(const bf16x8*)&Spl[c][t4 * 16 + lm][q * 8];
        }
        #pragma unroll
        for (int ti = 0; ti < 4; ti++) {
            #pragma unroll
            for (int tp = 0; tp < 4; tp++) {
                f32x4 y = __builtin_amdgcn_mfma_f32_16x16x32_bf16(cf[ti], sf[tp], (f32x4)0.f, 0, 0, 0);
                #pragma unroll
                for (int r = 0; r < 4; r++) {
                    int i = ti * 16 + q * 4 + r;
                    size_t idx = (rowbase + t0 + i) * DINNER + hd * 64 + tp * 16 + lm;
                    ysD[idx] = (__bf16)((float)ysD[idx] + y[r]);
                }
            }
        }
    }
}

// ---------------- launch ----------------
extern "C" void kernel_launch(void* const* d_in, const int* in_sizes, int n_in,
                              void* d_out, int out_size, void* d_ws, size_t ws_size,
                              hipStream_t stream) {
    const float* x_prefix    = (const float*)d_in[0];
    const float* y_aux       = (const float*)d_in[1];
    const float* pre_conv_w  = (const float*)d_in[2];
    const float* pre_conv_b  = (const float*)d_in[3];
    const float* patch_w     = (const float*)d_in[4];
    const float* patch_b     = (const float*)d_in[5];
    const float* mask_token  = (const float*)d_in[6];
    const float* aux_w       = (const float*)d_in[7];
    const float* aux_b       = (const float*)d_in[8];
    const float* patch_out_w = (const float*)d_in[9];
    const float* patch_out_b = (const float*)d_in[10];
    const float* w_norm[2]   = {(const float*)d_in[11], (const float*)d_in[20]};
    const float* w_inproj[2] = {(const float*)d_in[12], (const float*)d_in[21]};
    const float* w_convw[2]  = {(const float*)d_in[13], (const float*)d_in[22]};
    const float* w_convb[2]  = {(const float*)d_in[14], (const float*)d_in[23]};
    const float* w_dtb[2]    = {(const float*)d_in[15], (const float*)d_in[24]};
    const float* w_alog[2]   = {(const float*)d_in[16], (const float*)d_in[25]};
    const float* w_D[2]      = {(const float*)d_in[17], (const float*)d_in[26]};
    const float* w_gnorm[2]  = {(const float*)d_in[18], (const float*)d_in[27]};
    const float* w_outproj[2]= {(const float*)d_in[19], (const float*)d_in[28]};

    char* p = (char*)d_ws;
    auto alloc = [&](size_t bytes) { char* r = p; p += (bytes + 255) & ~255ULL; return r; };
    __bf16* A_patch  = (__bf16*)alloc((size_t)3072 * 4096 * 2);
    __bf16* WpreT    = (__bf16*)alloc((size_t)256 * 64 * 2);
    __bf16* WtT      = (__bf16*)alloc((size_t)256 * 4096 * 2);
    __bf16* inprojT  = (__bf16*)alloc((size_t)4 * 1152 * 256 * 2);
    __bf16* outprojT = (__bf16*)alloc((size_t)4 * 256 * 512 * 2);
    __bf16* poT      = (__bf16*)alloc((size_t)128 * 512 * 2);
    float*  h_all    = (float*)alloc((size_t)MALL * 256 * 4);
    __bf16* u        = (__bf16*)alloc((size_t)MALL * 256 * 2);
    __bf16* zxb      = (__bf16*)alloc((size_t)MALL * ZXW * 2);
    float*  dtc      = (float*)alloc((size_t)MALL * 8 * 4);
    __bf16* ysD      = (__bf16*)alloc((size_t)MALL * DINNER * 2);
    __bf16* y2       = (__bf16*)alloc((size_t)MALL * DINNER * 2);
    __bf16* ChatF    = (__bf16*)alloc((size_t)64 * 8 * 2048 * 2);
    __bf16* ChatB    = (__bf16*)alloc((size_t)64 * 2 * 2048 * 2);
    float*  dSF      = (float*)alloc((size_t)64 * 8 * 2048 * 4);
    float*  dSB      = (float*)alloc((size_t)64 * 2 * 2048 * 4);
    float*  DcsF     = (float*)alloc((size_t)64 * 8 * 4);
    float*  DcsB     = (float*)alloc((size_t)64 * 2 * 4);

    // 1) prep: weights + d_out bias + h_all background (bias/mask + aux)
    prep_all<<<256 + 1152 + 512 + 64 + 64 + 512 + MALL, 256, 0, stream>>>(
        pre_conv_w, patch_w, w_inproj[0], w_inproj[1], w_outproj[0], w_outproj[1],
        patch_out_w, patch_out_b, y_aux, aux_w, aux_b, patch_b, mask_token,
        WpreT, WtT, inprojT, outprojT, poT, (float*)d_out, h_all);
    // 2) pre-conv GEMM with fused im2row (silu+bf16 -> A_patch)
    preconv_gemm<<<dim3(2, (BSZ * TPREF) / 128), 256, 0, stream>>>(
        x_prefix, WpreT, pre_conv_b, A_patch);
    // 3) patch GEMM: split-K 8, atomicAdd into pre-initialized h_all (row remap)
    gemm_mfma<<<dim3(2, 24, 8), 256, 0, stream>>>(
        A_patch, WtT, h_all, nullptr, 256, 4096, 256, 16);

    for (int i = 0; i < 2; i++) {
        const __bf16* ipTf = inprojT + (size_t)(0 * 2 + i) * 1152 * 256;
        const __bf16* ipTb = inprojT + (size_t)(1 * 2 + i) * 1152 * 256;
        const __bf16* opTf = outprojT + (size_t)(0 * 2 + i) * 256 * 512;
        const __bf16* opTb = outprojT + (size_t)(1 * 2 + i) * 256 * 512;
        rmsnorm_all<<<MALL / 4, 256, 0, stream>>>(h_all, w_norm[0] + i * 256, w_norm[1] + i * 256, u);
        gemm_inproj<<<dim3(9, MALL / 128), 256, 0, stream>>>(u, ipTf, ipTb, zxb, dtc);
        scan_local<<<dim3(80, NHEADS), 256, 0, stream>>>(
            zxb,
            w_convw[0] + i * CONVDIM * 4, w_convb[0] + i * CONVDIM,
            w_convw[1] + i * CONVDIM * 4, w_convb[1] + i * CONVDIM,
            dtc,
            w_dtb[0] + i * 8, w_dtb[1] + i * 8,
            w_alog[0] + i * 8, w_alog[1] + i * 8,
            w_D[0] + i * 8, w_D[1] + i * 8,
            ysD, ChatF, ChatB, dSF, dSB, DcsF, DcsB, i);
        scan_tail<<<128, 256, 0, stream>>>(dSF, dSB, DcsF, DcsB, ChatF, ChatB, ysD, i);
        int gn = (i == 0) ? (MALL / 4) : 512;
        gatednorm_all<<<gn, 256, 0, stream>>>(
            ysD, zxb, w_gnorm[0] + i * DINNER, w_gnorm[1] + i * DINNER, y2, i);
        int oy = (i == 0) ? (MALL / 128) : 16;
        gemm_outproj<<<dim3(2, oy), 256, 0, stream>>>(y2, opTf, opTb, h_all, i);
    }

    // final: fused hcat gather + patch_out GEMM, split-K 4, atomic into bias-initialized d_out
    final_gemm<<<dim3(1, 8, 4), 256, 0, stream>>>(h_all, poT, (float*)d_out);
}

// Round 8
// 321.704 us; speedup vs baseline: 1.1341x; 1.0015x over previous
//
#include <hip/hip_runtime.h>
#include <hip/hip_bf16.h>
#include <math.h>

// ---------------- constants ----------------
#define BSZ      8
#define TPREF    6144
#define CIN      8
#define DMODEL   256
#define DINNER   512
#define DSTATE   32
#define NHEADS   8
#define HEADDIM  64
#define CONVDIM  576
#define DPROJ    1096
#define ZXW      1088              // bf16 zx width (z 0..511 | xBC 512..1087)
#define NTOK     512
#define NVIS     384
#define TBWD     128
#define MFWD     (BSZ * NTOK)      // 4096 rows
#define MBWD     (BSZ * TBWD)      // 1024 rows
#define MALL     (MFWD + MBWD)     // 5120 rows

typedef float f32x4 __attribute__((ext_vector_type(4)));
typedef __bf16 bf16x8 __attribute__((ext_vector_type(8)));

__device__ __forceinline__ float silu_f(float x) { return x / (1.f + expf(-x)); }

#define ASYNC16(gp, lp) \
    __builtin_amdgcn_global_load_lds((const __attribute__((address_space(1))) void*)(gp), \
                                     (__attribute__((address_space(3))) void*)(lp), 16, 0, 0)

// ---------------- generic bf16 MFMA GEMM (NT): C[m,n] = sum_k A[m,k]*Bt[n,k] ----------------
// flags: 2=atomicAdd; 4=silu(v+bias)+bf16 store; 16=atomicAdd into h_all with (b,tok)->row remap
__global__ __launch_bounds__(256) void gemm_mfma(
    const __bf16* __restrict__ A, const __bf16* __restrict__ Bt,
    float* __restrict__ C, const float* __restrict__ bias,
    int N, int K, int ldc, int flags) {
    __shared__ char sm[16384];
    int tid = threadIdx.x;
    int m0 = blockIdx.y * 128, n0 = blockIdx.x * 128;
    int klen = K / gridDim.z;
    int kbeg = blockIdx.z * klen;
    int w = tid >> 6, l = tid & 63;
    int wm = w >> 1, wn = w & 1;
    int lm = l & 15, q = l >> 4;

    f32x4 acc[4][4];
    #pragma unroll
    for (int i = 0; i < 4; i++)
        #pragma unroll
        for (int j = 0; j < 4; j++) acc[i][j] = (f32x4)0.f;

    for (int k0 = 0; k0 < klen; k0 += 32) {
        int kb = kbeg + k0;
        #pragma unroll
        for (int i = 0; i < 2; i++) {
            int s = i * 256 + tid;
            ASYNC16(A + (size_t)(m0 + (s >> 2)) * K + kb + (s & 3) * 8, sm + s * 16);
        }
        #pragma unroll
        for (int i = 0; i < 2; i++) {
            int s = i * 256 + tid;
            ASYNC16(Bt + (size_t)(n0 + (s >> 2)) * K + kb + (s & 3) * 8, sm + 8192 + s * 16);
        }
        __syncthreads();
        bf16x8 af[4], bfr[4];
        #pragma unroll
        for (int mf = 0; mf < 4; mf++)
            af[mf] = *(const bf16x8*)(sm + (wm * 64 + mf * 16 + lm) * 64 + q * 16);
        #pragma unroll
        for (int nf = 0; nf < 4; nf++)
            bfr[nf] = *(const bf16x8*)(sm + 8192 + (wn * 64 + nf * 16 + lm) * 64 + q * 16);
        #pragma unroll
        for (int mf = 0; mf < 4; mf++)
            #pragma unroll
            for (int nf = 0; nf < 4; nf++)
                acc[mf][nf] = __builtin_amdgcn_mfma_f32_16x16x32_bf16(af[mf], bfr[nf], acc[mf][nf], 0, 0, 0);
        __syncthreads();
    }

    #pragma unroll
    for (int mf = 0; mf < 4; mf++) {
        int mbase = m0 + wm * 64 + mf * 16 + q * 4;
        #pragma unroll
        for (int nf = 0; nf < 4; nf++) {
            int n = n0 + wn * 64 + nf * 16 + lm;
            if (n < N) {
                #pragma unroll
                for (int r = 0; r < 4; r++) {
                    float v = acc[mf][nf][r];
                    if (flags & 4) {
                        v = silu_f(v + bias[n]);
                        ((__bf16*)C)[(size_t)(mbase + r) * ldc + n] = (__bf16)v;
                    } else if (flags & 16) {
                        int mm = mbase + r;
                        int bb = mm / NVIS, tk = mm - bb * NVIS;   // m = b*384+tok
                        atomicAdd(C + ((size_t)(bb * NTOK + tk)) * 256 + n, v);
                    } else if (flags & 2) {
                        atomicAdd(C + (size_t)(mbase + r) * ldc + n, v);
                    } else {
                        C[(size_t)(mbase + r) * ldc + n] = v;
                    }
                }
            }
        }
    }
}

// ---------------- pre-conv GEMM with fused im2row ----------------
__global__ __launch_bounds__(256) void preconv_gemm(
    const float* __restrict__ xp, const __bf16* __restrict__ WpreT,
    const float* __restrict__ bias, __bf16* __restrict__ Apatch) {
    __shared__ char sm[32768];   // A: [2][128][32]bf16 = 16KB @0, B: same @16384
    int tid = threadIdx.x;
    int m0 = blockIdx.y * 128, n0 = blockIdx.x * 128;
    int w = tid >> 6, l = tid & 63;
    int wm = w >> 1, wn = w & 1, lm = l & 15, q = l >> 4;

    #pragma unroll
    for (int i = 0; i < 4; i++) {
        int s = i * 256 + tid;
        int kh = s >> 9, row = (s & 511) >> 2, within = s & 3;
        ASYNC16(WpreT + (size_t)(n0 + row) * 64 + kh * 32 + within * 8, sm + 16384 + s * 16);
    }
    if (tid < 128) {
        int m = m0 + tid;
        int b = m / TPREF, t = m - b * TPREF;
        __bf16 d[64];
        #pragma unroll
        for (int j = 40; j < 64; j++) d[j] = (__bf16)0.f;
        #pragma unroll
        for (int k = 0; k < 5; k++) {
            int tt = t - 2 + k;
            bool ok = (tt >= 0) && (tt < TPREF);
            const float* s = xp + ((size_t)b * TPREF + tt) * 8;
            #pragma unroll
            for (int i = 0; i < 8; i++)
                d[i * 5 + k] = ok ? (__bf16)s[i] : (__bf16)0.f;
        }
        uint4* o0 = (uint4*)(sm + tid * 64);
        uint4* o1 = (uint4*)(sm + 8192 + tid * 64);
        #pragma unroll
        for (int k = 0; k < 4; k++) { o0[k] = ((const uint4*)d)[k]; o1[k] = ((const uint4*)d)[4 + k]; }
    }
    __syncthreads();

    f32x4 acc[4][4];
    #pragma unroll
    for (int i = 0; i < 4; i++)
        #pragma unroll
        for (int j = 0; j < 4; j++) acc[i][j] = (f32x4)0.f;
    #pragma unroll
    for (int kh = 0; kh < 2; kh++) {
        bf16x8 af[4], bfr[4];
        #pragma unroll
        for (int mf = 0; mf < 4; mf++)
            af[mf] = *(const bf16x8*)(sm + kh * 8192 + (wm * 64 + mf * 16 + lm) * 64 + q * 16);
        #pragma unroll
        for (int nf = 0; nf < 4; nf++)
            bfr[nf] = *(const bf16x8*)(sm + 16384 + kh * 8192 + (wn * 64 + nf * 16 + lm) * 64 + q * 16);
        #pragma unroll
        for (int mf = 0; mf < 4; mf++)
            #pragma unroll
            for (int nf = 0; nf < 4; nf++)
                acc[mf][nf] = __builtin_amdgcn_mfma_f32_16x16x32_bf16(af[mf], bfr[nf], acc[mf][nf], 0, 0, 0);
    }
    #pragma unroll
    for (int mf = 0; mf < 4; mf++) {
        int mbase = m0 + wm * 64 + mf * 16 + q * 4;
        #pragma unroll
        for (int nf = 0; nf < 4; nf++) {
            int n = n0 + wn * 64 + nf * 16 + lm;
            #pragma unroll
            for (int r = 0; r < 4; r++) {
                float v = silu_f(acc[mf][nf][r] + bias[n]);
                Apatch[(size_t)(mbase + r) * 256 + n] = (__bf16)v;
            }
        }
    }
}

// ---------------- final GEMM: hcat gather fused; split-K 8 (dir x k-quarter) ----------------
__global__ __launch_bounds__(256) void final_gemm(
    const float* __restrict__ h_all, const __bf16* __restrict__ poT,
    float* __restrict__ out) {
    __shared__ __bf16 Asm_[128][40];
    __shared__ char Bsm[8192];
    int tid = threadIdx.x;
    int m0 = blockIdx.y * 128;
    int z = blockIdx.z;                 // 0..7
    int dir = z >> 2, ks = z & 3;
    int koff = ks * 64;
    int w = tid >> 6, l = tid & 63;
    int wm = w >> 1, wn_ = w & 1, lm = l & 15, q = l >> 4;
    f32x4 acc[4][4];
    #pragma unroll
    for (int i = 0; i < 4; i++)
        #pragma unroll
        for (int j = 0; j < 4; j++) acc[i][j] = (f32x4)0.f;

    int r = tid >> 1, half = tid & 1;
    int m = m0 + r;
    int b = m >> 7, jj = m & 127;
    size_t arow = (dir == 0) ? ((size_t)(b * NTOK + NVIS + jj) * 256)
                             : ((size_t)MFWD * 256 + (size_t)(b * TBWD + (TBWD - 1 - jj)) * 256);
    for (int k0 = 0; k0 < 64; k0 += 32) {
        {
            const float4* sp = (const float4*)(h_all + arow + koff + k0 + half * 16);
            float4 v0 = sp[0], v1 = sp[1], v2 = sp[2], v3 = sp[3];
            union { uint4 u; __bf16 hh[8]; } d0, d1;
            d0.hh[0] = (__bf16)v0.x; d0.hh[1] = (__bf16)v0.y; d0.hh[2] = (__bf16)v0.z; d0.hh[3] = (__bf16)v0.w;
            d0.hh[4] = (__bf16)v1.x; d0.hh[5] = (__bf16)v1.y; d0.hh[6] = (__bf16)v1.z; d0.hh[7] = (__bf16)v1.w;
            d1.hh[0] = (__bf16)v2.x; d1.hh[1] = (__bf16)v2.y; d1.hh[2] = (__bf16)v2.z; d1.hh[3] = (__bf16)v2.w;
            d1.hh[4] = (__bf16)v3.x; d1.hh[5] = (__bf16)v3.y; d1.hh[6] = (__bf16)v3.z; d1.hh[7] = (__bf16)v3.w;
            *(uint4*)&Asm_[r][half * 16] = d0.u;
            *(uint4*)&Asm_[r][half * 16 + 8] = d1.u;
        }
        #pragma unroll
        for (int i = 0; i < 2; i++) {
            int s = i * 256 + tid;
            ASYNC16(poT + (size_t)(s >> 2) * 512 + dir * 256 + koff + k0 + (s & 3) * 8, Bsm + s * 16);
        }
        __syncthreads();
        bf16x8 af[4], bfr[4];
        #pragma unroll
        for (int mf = 0; mf < 4; mf++)
            af[mf] = *(const bf16x8*)&Asm_[wm * 64 + mf * 16 + lm][q * 8];
        #pragma unroll
        for (int nf = 0; nf < 4; nf++)
            bfr[nf] = *(const bf16x8*)(Bsm + (wn_ * 64 + nf * 16 + lm) * 64 + q * 16);
        #pragma unroll
        for (int mf = 0; mf < 4; mf++)
            #pragma unroll
            for (int nf = 0; nf < 4; nf++)
                acc[mf][nf] = __builtin_amdgcn_mfma_f32_16x16x32_bf16(af[mf], bfr[nf], acc[mf][nf], 0, 0, 0);
        __syncthreads();
    }
    #pragma unroll
    for (int mf = 0; mf < 4; mf++) {
        int mbase = m0 + wm * 64 + mf * 16 + q * 4;
        #pragma unroll
        for (int nf = 0; nf < 4; nf++) {
            int n = wn_ * 64 + nf * 16 + lm;
            #pragma unroll
            for (int rr = 0; rr < 4; rr++)
                atomicAdd(out + (size_t)(mbase + rr) * 128 + n, acc[mf][nf][rr]);
        }
    }
}

// ---------------- inproj GEMM: 128x128 tile, K=256; bf16 zxb + fp32 dtc outputs ----------------
__global__ __launch_bounds__(256) void gemm_inproj(
    const __bf16* __restrict__ u, const __bf16* __restrict__ ipTf,
    const __bf16* __restrict__ ipTb, __bf16* __restrict__ zxb, float* __restrict__ dtc) {
    __shared__ char sm[16384];
    int tid = threadIdx.x;
    int m0 = blockIdx.y * 128, n0 = blockIdx.x * 128;
    const __bf16* Bt = (m0 >= MFWD) ? ipTb : ipTf;
    int w = tid >> 6, l = tid & 63;
    int wm = w >> 1, wn = w & 1, lm = l & 15, q = l >> 4;
    f32x4 acc[4][4];
    #pragma unroll
    for (int i = 0; i < 4; i++)
        #pragma unroll
        for (int j = 0; j < 4; j++) acc[i][j] = (f32x4)0.f;
    for (int k0 = 0; k0 < 256; k0 += 32) {
        #pragma unroll
        for (int i = 0; i < 2; i++) {
            int s = i * 256 + tid;
            ASYNC16(u + (size_t)(m0 + (s >> 2)) * 256 + k0 + (s & 3) * 8, sm + s * 16);
        }
        #pragma unroll
        for (int i = 0; i < 2; i++) {
            int s = i * 256 + tid;
            ASYNC16(Bt + (size_t)(n0 + (s >> 2)) * 256 + k0 + (s & 3) * 8, sm + 8192 + s * 16);
        }
        __syncthreads();
        bf16x8 af[4], bfr[4];
        #pragma unroll
        for (int mf = 0; mf < 4; mf++)
            af[mf] = *(const bf16x8*)(sm + (wm * 64 + mf * 16 + lm) * 64 + q * 16);
        #pragma unroll
        for (int nf = 0; nf < 4; nf++)
            bfr[nf] = *(const bf16x8*)(sm + 8192 + (wn * 64 + nf * 16 + lm) * 64 + q * 16);
        #pragma unroll
        for (int mf = 0; mf < 4; mf++)
            #pragma unroll
            for (int nf = 0; nf < 4; nf++)
                acc[mf][nf] = __builtin_amdgcn_mfma_f32_16x16x32_bf16(af[mf], bfr[nf], acc[mf][nf], 0, 0, 0);
        __syncthreads();
    }
    #pragma unroll
    for (int mf = 0; mf < 4; mf++) {
        int mbase = m0 + wm * 64 + mf * 16 + q * 4;
        #pragma unroll
        for (int nf = 0; nf < 4; nf++) {
            int n = n0 + wn * 64 + nf * 16 + lm;
            #pragma unroll
            for (int r = 0; r < 4; r++) {
                float v = acc[mf][nf][r];
                if (n < ZXW) zxb[(size_t)(mbase + r) * ZXW + n] = (__bf16)v;
                else if (n < DPROJ) dtc[(size_t)(mbase + r) * 8 + (n - ZXW)] = v;
            }
        }
    }
}

// ---------------- outproj GEMM: 128x128 tile, K=512 split-K 2, layer-aware rows, atomic residual ----------------
__global__ __launch_bounds__(256) void gemm_outproj(
    const __bf16* __restrict__ y2, const __bf16* __restrict__ opTf,
    const __bf16* __restrict__ opTb, float* __restrict__ C, int layer) {
    __shared__ char sm[16384];
    int tid = threadIdx.x;
    int yb = blockIdx.y;
    int m0 = (layer == 0) ? yb * 128
                          : ((yb < 8) ? (yb * 512 + 384) : (MFWD + (yb - 8) * 128));
    int n0 = blockIdx.x * 128;
    int kbeg = blockIdx.z * 256;
    const __bf16* Bt = (m0 >= MFWD) ? opTb : opTf;
    int w = tid >> 6, l = tid & 63;
    int wm = w >> 1, wn = w & 1, lm = l & 15, q = l >> 4;
    f32x4 acc[4][4];
    #pragma unroll
    for (int i = 0; i < 4; i++)
        #pragma unroll
        for (int j = 0; j < 4; j++) acc[i][j] = (f32x4)0.f;
    for (int k0 = 0; k0 < 256; k0 += 32) {
        int kb = kbeg + k0;
        #pragma unroll
        for (int i = 0; i < 2; i++) {
            int s = i * 256 + tid;
            ASYNC16(y2 + (size_t)(m0 + (s >> 2)) * 512 + kb + (s & 3) * 8, sm + s * 16);
        }
        #pragma unroll
        for (int i = 0; i < 2; i++) {
            int s = i * 256 + tid;
            ASYNC16(Bt + (size_t)(n0 + (s >> 2)) * 512 + kb + (s & 3) * 8, sm + 8192 + s * 16);
        }
        __syncthreads();
        bf16x8 af[4], bfr[4];
        #pragma unroll
        for (int mf = 0; mf < 4; mf++)
            af[mf] = *(const bf16x8*)(sm + (wm * 64 + mf * 16 + lm) * 64 + q * 16);
        #pragma unroll
        for (int nf = 0; nf < 4; nf++)
            bfr[nf] = *(const bf16x8*)(sm + 8192 + (wn * 64 + nf * 16 + lm) * 64 + q * 16);
        #pragma unroll
        for (int mf = 0; mf < 4; mf++)
            #pragma unroll
            for (int nf = 0; nf < 4; nf++)
                acc[mf][nf] = __builtin_amdgcn_mfma_f32_16x16x32_bf16(af[mf], bfr[nf], acc[mf][nf], 0, 0, 0);
        __syncthreads();
    }
    #pragma unroll
    for (int mf = 0; mf < 4; mf++) {
        int mbase = m0 + wm * 64 + mf * 16 + q * 4;
        #pragma unroll
        for (int nf = 0; nf < 4; nf++) {
            int n = n0 + wn * 64 + nf * 16 + lm;
            #pragma unroll
            for (int r = 0; r < 4; r++) {
                size_t ci = (size_t)(mbase + r) * DMODEL + n;
                atomicAdd(C + ci, acc[mf][nf][r]);
            }
        }
    }
}

// ---------------- elementwise norms ----------------
__global__ __launch_bounds__(256) void rmsnorm_all(
    const float* __restrict__ h, const float* __restrict__ wf,
    const float* __restrict__ wb, __bf16* __restrict__ u) {
    int row = blockIdx.x * 4 + (threadIdx.x >> 6);
    int lane = threadIdx.x & 63;
    const float* w = (row >= MFWD) ? wb : wf;
    float4 v = ((const float4*)(h + (size_t)row * 256))[lane];
    float ss = v.x * v.x + v.y * v.y + v.z * v.z + v.w * v.w;
    #pragma unroll
    for (int off = 32; off >= 1; off >>= 1) ss += __shfl_xor(ss, off);
    float rs = rsqrtf(ss * (1.f / 256.f) + 1e-5f);
    float4 wv = ((const float4*)w)[lane];
    __bf16 o4[4] = {(__bf16)(v.x * rs * wv.x), (__bf16)(v.y * rs * wv.y),
                    (__bf16)(v.z * rs * wv.z), (__bf16)(v.w * rs * wv.w)};
    *(uint2*)(u + (size_t)row * 256 + lane * 4) = *(uint2*)o4;
}

// gatednorm: layer 0 covers all rows (grid 1280); layer 1 covers only the 2048
// rows consumed by outproj layer 1 (grid 512): fwd rows b*512+384..511, all bwd rows.
__global__ __launch_bounds__(256) void gatednorm_all(
    const __bf16* __restrict__ ysD, const __bf16* __restrict__ zxb,
    const float* __restrict__ gwf, const float* __restrict__ gwb,
    __bf16* __restrict__ y2, int layer) {
    int blk = blockIdx.x;
    int sub = threadIdx.x >> 6;
    int row;
    if (layer == 0) {
        row = blk * 4 + sub;
    } else {
        if (blk < 256) { int b = blk >> 5; row = b * 512 + 384 + (blk & 31) * 4 + sub; }
        else           { row = MFWD + (blk - 256) * 4 + sub; }
    }
    int lane = threadIdx.x & 63;
    const float* gw = (row >= MFWD) ? gwb : gwf;
    union { uint4 u; __bf16 hh[8]; } yv, zv;
    yv.u = *(const uint4*)(ysD + (size_t)row * 512 + lane * 8);
    zv.u = *(const uint4*)(zxb + (size_t)row * ZXW + lane * 8);
    float g[8];
    #pragma unroll
    for (int j = 0; j < 8; j++) g[j] = (float)yv.hh[j] * silu_f((float)zv.hh[j]);
    float ss = 0.f;
    #pragma unroll
    for (int j = 0; j < 8; j++) ss += g[j] * g[j];
    #pragma unroll
    for (int off = 32; off >= 1; off >>= 1) ss += __shfl_xor(ss, off);
    float rs = rsqrtf(ss * (1.f / 512.f) + 1e-5f);
    const float4* gr = (const float4*)(gw + lane * 8);
    float4 g0 = gr[0], g1 = gr[1];
    union { uint4 u; __bf16 hh[8]; } d;
    d.hh[0] = (__bf16)(g[0] * rs * g0.x); d.hh[1] = (__bf16)(g[1] * rs * g0.y);
    d.hh[2] = (__bf16)(g[2] * rs * g0.z); d.hh[3] = (__bf16)(g[3] * rs * g0.w);
    d.hh[4] = (__bf16)(g[4] * rs * g1.x); d.hh[5] = (__bf16)(g[5] * rs * g1.y);
    d.hh[6] = (__bf16)(g[6] * rs * g1.z); d.hh[7] = (__bf16)(g[7] * rs * g1.w);
    *(uint4*)(y2 + (size_t)row * 512 + lane * 8) = d.u;
}

// ---------------- segmented prep kernel (all coalesced) ----------------
// WtT 256 | inprojT 1152 | outprojT 512 | poT 64 | WpreT 64 | dout 512 | hinit 5120
__global__ void prep_all(const float* __restrict__ pre_conv_w, const float* __restrict__ patch_w,
                         const float* __restrict__ ip0, const float* __restrict__ ip1,
                         const float* __restrict__ op0, const float* __restrict__ op1,
                         const float* __restrict__ pow_, const float* __restrict__ pob,
                         const float* __restrict__ y_aux, const float* __restrict__ aux_w,
                         const float* __restrict__ aux_b,
                         const float* __restrict__ patch_b, const float* __restrict__ mtok,
                         __bf16* __restrict__ WpreT, __bf16* __restrict__ WtT,
                         __bf16* __restrict__ inprojT, __bf16* __restrict__ outprojT,
                         __bf16* __restrict__ poT, float* __restrict__ dout,
                         float* __restrict__ h_all) {
    __shared__ float tile[32][33];
    int bx = blockIdx.x, tid = threadIdx.x;
    int tx = tid & 31, ty = tid >> 5;
    if (bx < 256) {
        int o = bx, c = tid;
        float f[16];
        const float4* s = (const float4*)(patch_w + (size_t)o * 4096 + c * 16);
        #pragma unroll
        for (int j = 0; j < 4; j++) *(float4*)&f[j * 4] = s[j];
        #pragma unroll
        for (int k = 0; k < 16; k++)
            WtT[(size_t)o * 4096 + k * 256 + c] = (__bf16)f[k];
        return;
    }
    bx -= 256;
    if (bx < 1152) {
        int seg = bx / 288, rem = bx % 288;
        int n0 = (rem / 8) * 32, k0 = (rem % 8) * 32;
        const float* src = (seg < 2 ? ip0 : ip1) + (size_t)(seg & 1) * 256 * DPROJ;
        #pragma unroll
        for (int j = 0; j < 4; j++) {
            int r = ty + j * 8;
            int n = n0 + tx;
            tile[r][tx] = (n < DPROJ) ? src[(size_t)(k0 + r) * DPROJ + n] : 0.f;
        }
        __syncthreads();
        __bf16* dst = inprojT + (size_t)seg * 1152 * 256;
        #pragma unroll
        for (int j = 0; j < 4; j++) {
            int r = ty + j * 8;
            dst[(size_t)(n0 + r) * 256 + k0 + tx] = (__bf16)tile[tx][r];
        }
        return;
    }
    bx -= 1152;
    if (bx < 512) {
        int s = bx / 128, rem = bx % 128;
        int n0 = (rem / 16) * 32, k0 = (rem % 16) * 32;
        const float* src = (s < 2 ? op0 : op1) + (size_t)(s & 1) * DINNER * DMODEL;
        #pragma unroll
        for (int j = 0; j < 4; j++) {
            int r = ty + j * 8;
            tile[r][tx] = src[(size_t)(k0 + r) * 256 + n0 + tx];
        }
        __syncthreads();
        __bf16* dst = outprojT + (size_t)s * 256 * 512;
        #pragma unroll
        for (int j = 0; j < 4; j++) {
            int r = ty + j * 8;
            dst[(size_t)(n0 + r) * 512 + k0 + tx] = (__bf16)tile[tx][r];
        }
        return;
    }
    bx -= 512;
    if (bx < 64) {
        int n0 = (bx / 16) * 32, k0 = (bx % 16) * 32;
        #pragma unroll
        for (int j = 0; j < 4; j++) {
            int r = ty + j * 8;
            tile[r][tx] = pow_[(size_t)(k0 + r) * 128 + n0 + tx];
        }
        __syncthreads();
        #pragma unroll
        for (int j = 0; j < 4; j++) {
            int r = ty + j * 8;
            poT[(size_t)(n0 + r) * 512 + k0 + tx] = (__bf16)tile[tx][r];
        }
        return;
    }
    bx -= 64;
    if (bx < 64) {
        int idx = bx * 256 + tid;
        int o = idx >> 6, kk = idx & 63;
        WpreT[idx] = (kk < 40) ? (__bf16)pre_conv_w[o * 40 + kk] : (__bf16)0.f;
        return;
    }
    bx -= 64;
    if (bx < 512) {
        int idx = bx * 256 + tid;
        dout[idx] = pob[idx & 127];
        return;
    }
    bx -= 512;
    {   // h_all init: visible fwd rows = patch_b+aux (GEMM atomically adds patch term);
        // masked fwd rows and all bwd rows = mask_token+aux
        int row = bx, o = tid;
        int b; bool masked;
        if (row < MFWD) { b = row >> 9; int tok = row & 511; masked = (tok >= NVIS); }
        else { b = (row - MFWD) >> 7; masked = true; }
        float acc = aux_b[o];
        #pragma unroll
        for (int i = 0; i < 16; i++) acc += y_aux[b * 16 + i] * aux_w[i * 256 + o];
        float v = (masked ? mtok[o] : patch_b[o]) + silu_f(acc);
        h_all[(size_t)row * 256 + o] = v;
    }
}

// ---------------- chunked SSD scan phase A with fused depthwise conv: 4 waves/block ----------------
// grid (80, 8). Stages raw X/BC slices from zxb cooperatively (uint4), conv k=4 + silu in-block.
__global__ __launch_bounds__(256) void scan_local(
    const __bf16* __restrict__ zxb,
    const float* __restrict__ cwf, const float* __restrict__ cbf,
    const float* __restrict__ cwb, const float* __restrict__ cbb,
    const float* __restrict__ dtc,
    const float* __restrict__ dtbf, const float* __restrict__ dtbb,
    const float* __restrict__ Alogf, const float* __restrict__ Alogb,
    const float* __restrict__ Dpf, const float* __restrict__ Dpb,
    __bf16* __restrict__ ysD,
    __bf16* __restrict__ ChatF, __bf16* __restrict__ ChatB,
    float* __restrict__ dSF, float* __restrict__ dSB,
    float* __restrict__ DcsF, float* __restrict__ DcsB, int layer) {
    int id = blockIdx.x, hd = blockIdx.y;
    int b, c, T, NC; size_t rowbase;
    __bf16* Chat; float *dS, *Dcs;
    const float *dtb, *Alog, *Dp, *cw, *cb;
    if (id < 64) { b = id >> 3; c = id & 7; T = NTOK; NC = 8; rowbase = (size_t)b * NTOK;
                   Chat = ChatF; dS = dSF; Dcs = DcsF;
                   dtb = dtbf; Alog = Alogf; Dp = Dpf; cw = cwf; cb = cbf; }
    else { int i2 = id - 64; b = i2 >> 1; c = i2 & 1; T = TBWD; NC = 2;
           rowbase = (size_t)MFWD + (size_t)b * TBWD;
           Chat = ChatB; dS = dSB; Dcs = DcsB;
           dtb = dtbb; Alog = Alogb; Dp = Dpb; cw = cwb; cb = cbb; }
    bool skipY = (layer == 1) && (id < 64) && (c < 6);
    int bh = b * 8 + hd;
    int t0 = c * 64;
    int tid = threadIdx.x;
    int w = tid >> 6, l = tid & 63;
    int lm = l & 15, q = l >> 4;
    float A = -expf(Alog[hd]);
    float Dh = Dp[hd];

    __shared__ char smem[40704];
    __bf16 (*Xl)[72]  = (__bf16(*)[72])(smem);            // Xl[ch][t] post-conv
    __bf16 (*BCl)[72] = (__bf16(*)[72])(smem + 9216);     // BCl[t][ch] post-conv
    __bf16 (*Pl)[72]  = (__bf16(*)[72])(smem + 9216);     // overwrites BCl after reads done
    __bf16 (*Wbl)[72] = (__bf16(*)[72])(smem + 18432);
    float* lcs = (float*)(smem + 23040);
    float* dts = (float*)(smem + 23296);
    __bf16 (*xraw)[64] = (__bf16(*)[64])(smem + 23552);   // 67x64 raw X (this head)
    __bf16 (*braw)[64] = (__bf16(*)[64])(smem + 32128);   // 67x64 raw BC

    // ---- stage raw slices: 1072 uint4 chunks over 256 threads ----
    for (int s = tid; s < 1072; s += 256) {
        int arr = (s >= 536) ? 1 : 0;
        int s2 = s - arr * 536;
        int r = s2 >> 3, seg = s2 & 7;
        int t = t0 - 3 + r;
        uint4 v = make_uint4(0u, 0u, 0u, 0u);
        if (t >= 0) {
            size_t col = arr ? (size_t)(1024 + seg * 8) : (size_t)(DINNER + hd * 64 + seg * 8);
            v = *(const uint4*)(zxb + (rowbase + t) * (size_t)ZXW + col);
        }
        if (arr) *(uint4*)&braw[r][seg * 8] = v;
        else     *(uint4*)&xraw[r][seg * 8] = v;
    }
    __syncthreads();

    // ---- conv X: ch = lane, t-quarter = wave; pack 16 outputs -> Xl[ch][t] ----
    {
        int cX = hd * 64 + l;
        float w0 = cw[cX * 4], w1 = cw[cX * 4 + 1], w2 = cw[cX * 4 + 2], w3 = cw[cX * 4 + 3];
        float cbv = cb[cX];
        int tb = w * 16;
        float a0 = (float)xraw[tb][l], a1 = (float)xraw[tb + 1][l], a2 = (float)xraw[tb + 2][l];
        union { uint4 u; __bf16 h[8]; } p0, p1;
        #pragma unroll
        for (int j = 0; j < 16; j++) {
            float a3 = (float)xraw[tb + j + 3][l];
            float acc = cbv + w0 * a0 + w1 * a1 + w2 * a2 + w3 * a3;
            if (j < 8) p0.h[j] = (__bf16)silu_f(acc);
            else       p1.h[j - 8] = (__bf16)silu_f(acc);
            a0 = a1; a1 = a2; a2 = a3;
        }
        *(uint4*)&Xl[l][tb]     = p0.u;
        *(uint4*)&Xl[l][tb + 8] = p1.u;
    }
    // ---- conv BC: ch = lane, t-quarter = wave -> BCl[t][ch] (transposed, scalar stores) ----
    {
        int cc = 512 + l;
        float w0 = cw[cc * 4], w1 = cw[cc * 4 + 1], w2 = cw[cc * 4 + 2], w3 = cw[cc * 4 + 3];
        float cbv = cb[cc];
        int tb = w * 16;
        float a0 = (float)braw[tb][l], a1 = (float)braw[tb + 1][l], a2 = (float)braw[tb + 2][l];
        #pragma unroll
        for (int j = 0; j < 16; j++) {
            float a3 = (float)braw[tb + j + 3][l];
            float acc = cbv + w0 * a0 + w1 * a1 + w2 * a2 + w3 * a3;
            BCl[tb + j][l] = (__bf16)silu_f(acc);
            a0 = a1; a1 = a2; a2 = a3;
        }
    }
    // ---- per-token dt + cumulative log-decay (redundant per wave; lane = token) ----
    float xdt = dtc[(rowbase + t0 + l) * 8 + hd] + dtb[hd];
    float dtv = (xdt > 20.f) ? xdt : log1pf(expf(xdt));
    float lc = A * dtv;
    #pragma unroll
    for (int off = 1; off < 64; off <<= 1) {
        float o = __shfl_up(lc, off);
        if (l >= off) lc += o;
    }
    float lc63 = __shfl(lc, 63);
    float wj = expf(lc63 - lc) * dtv;
    float eli = expf(lc);
    if (w == 0) {
        lcs[l] = lc; dts[l] = dtv;
        if (l == 0) Dcs[bh * NC + c] = expf(lc63);
    }
    __syncthreads();   // conv outputs + lcs/dts visible

    // ---- Chat write (wave w: channel group w*8..w*8+7 of C part) ----
    if (!skipY) {
        union { uint4 u; __bf16 h[8]; } s, d;
        s.u = *(const uint4*)&BCl[l][32 + w * 8];
        #pragma unroll
        for (int j = 0; j < 8; j++) d.h[j] = (__bf16)(eli * (float)s.h[j]);
        *(uint4*)(Chat + ((size_t)(bh * NC + c) * 64 + l) * 32 + w * 8) = d.u;
    }
    // ---- Wbl[n][t] build (wave w: n group w*8..w*8+7) ----
    {
        union { uint4 u; __bf16 h[8]; } s;
        s.u = *(const uint4*)&BCl[l][w * 8];
        #pragma unroll
        for (int j = 0; j < 8; j++) Wbl[w * 8 + j][l] = (__bf16)(wj * (float)s.h[j]);
    }
    // ---- P-phase register loads (must complete before Pl overwrites BCl) ----
    bf16x8 cfr, bfr[4];
    if (!skipY) {
        cfr = *(const bf16x8*)&BCl[w * 16 + lm][32 + q * 8];
        #pragma unroll
        for (int tj = 0; tj < 4; tj++)
            if (tj <= w) bfr[tj] = *(const bf16x8*)&BCl[tj * 16 + lm][q * 8];
    }
    __syncthreads();   // all BCl reads done; Wbl complete

    if (!skipY) {
        float lci[4];
        #pragma unroll
        for (int r = 0; r < 4; r++) lci[r] = lcs[w * 16 + q * 4 + r];
        #pragma unroll
        for (int tj = 0; tj < 4; tj++) {
            if (tj > w) {
                #pragma unroll
                for (int r = 0; r < 4; r++) Pl[w * 16 + q * 4 + r][tj * 16 + lm] = (__bf16)0.f;
                continue;
            }
            f32x4 g = __builtin_amdgcn_mfma_f32_16x16x32_bf16(cfr, bfr[tj], (f32x4)0.f, 0, 0, 0);
            int j = tj * 16 + lm;
            float lcj = lcs[j], dtj = dts[j];
            #pragma unroll
            for (int r = 0; r < 4; r++) {
                int i = w * 16 + q * 4 + r;
                float v = (j <= i) ? g[r] * expf(lci[r] - lcj) * dtj : 0.f;
                if (j == i) v += Dh;
                Pl[i][j] = (__bf16)v;
            }
        }
    }
    __syncthreads();   // Pl ready

    bf16x8 xf0[4], xf1[4];
    #pragma unroll
    for (int t4 = 0; t4 < 4; t4++) {
        xf0[t4] = *(const bf16x8*)&Xl[t4 * 16 + lm][q * 8];
        xf1[t4] = *(const bf16x8*)&Xl[t4 * 16 + lm][32 + q * 8];
    }
    if (!skipY) {
        bf16x8 pf0 = *(const bf16x8*)&Pl[w * 16 + lm][q * 8];
        bf16x8 pf1 = *(const bf16x8*)&Pl[w * 16 + lm][32 + q * 8];
        #pragma unroll
        for (int tp = 0; tp < 4; tp++) {
            f32x4 y = __builtin_amdgcn_mfma_f32_16x16x32_bf16(pf0, xf0[tp], (f32x4)0.f, 0, 0, 0);
            y = __builtin_amdgcn_mfma_f32_16x16x32_bf16(pf1, xf1[tp], y, 0, 0, 0);
            #pragma unroll
            for (int r = 0; r < 4; r++) {
                int i = w * 16 + q * 4 + r;
                ysD[(rowbase + t0 + i) * DINNER + hd * 64 + tp * 16 + lm] = (__bf16)y[r];
            }
        }
    }
    // ---- dS (wave w = tp) ----
    bf16x8 wf0[2], wf1[2];
    #pragma unroll
    for (int tn = 0; tn < 2; tn++) {
        wf0[tn] = *(const bf16x8*)&Wbl[tn * 16 + lm][q * 8];
        wf1[tn] = *(const bf16x8*)&Wbl[tn * 16 + lm][32 + q * 8];
    }
    float* dso = dS + (size_t)(bh * NC + c) * 2048;
    #pragma unroll
    for (int tn = 0; tn < 2; tn++) {
        f32x4 s = __builtin_amdgcn_mfma_f32_16x16x32_bf16(xf0[w], wf0[tn], (f32x4)0.f, 0, 0, 0);
        s = __builtin_amdgcn_mfma_f32_16x16x32_bf16(xf1[w], wf1[tn], s, 0, 0, 0);
        #pragma unroll
        for (int r = 0; r < 4; r++) {
            int pp = w * 16 + q * 4 + r, nn = tn * 16 + lm;
            dso[pp * 32 + nn] = s[r];
        }
    }
}

// ---------------- scan tail: recurrence + cross-chunk Y add ----------------
__global__ __launch_bounds__(256) void scan_tail(
    const float* __restrict__ dSF, const float* __restrict__ dSB,
    const float* __restrict__ DcsF, const float* __restrict__ DcsB,
    const __bf16* __restrict__ ChatF, const __bf16* __restrict__ ChatB,
    __bf16* __restrict__ ysD, int layer) {
    int blk = blockIdx.x;
    int dir = blk >= 64;
    int bh = blk & 63;
    int NC = dir ? 2 : 8;
    int T = dir ? TBWD : NTOK;
    int b = bh >> 3, hd = bh & 7;
    size_t rowbase = dir ? ((size_t)MFWD + (size_t)b * TBWD) : ((size_t)b * NTOK);
    const float* dS = dir ? dSB : dSF;
    const float* Dcs = dir ? DcsB : DcsF;
    const __bf16* Chat = dir ? ChatB : ChatF;
    int cmin = (layer == 1 && !dir) ? 6 : 1;
    int tid = threadIdx.x;
    __shared__ __bf16 Spl[8][64][40];
    {
        int p = tid >> 2, n0 = (tid & 3) * 8;
        float S[8];
        #pragma unroll
        for (int j = 0; j < 8; j++) S[j] = 0.f;
        for (int c = 0; c < NC; c++) {
            union { uint4 u; __bf16 hh[8]; } o;
            #pragma unroll
            for (int j = 0; j < 8; j++) o.hh[j] = (__bf16)S[j];
            *(uint4*)&Spl[c][p][n0] = o.u;
            float Dc = Dcs[bh * NC + c];
            const float4* dp = (const float4*)(dS + ((size_t)(bh * NC + c)) * 2048 + tid * 8);
            float4 d0 = dp[0], d1 = dp[1];
            S[0] = Dc * S[0] + d0.x; S[1] = Dc * S[1] + d0.y;
            S[2] = Dc * S[2] + d0.z; S[3] = Dc * S[3] + d0.w;
            S[4] = Dc * S[4] + d1.x; S[5] = Dc * S[5] + d1.y;
            S[6] = Dc * S[6] + d1.z; S[7] = Dc * S[7] + d1.w;
        }
    }
    __syncthreads();
    int w = tid >> 6, l = tid & 63, lm = l & 15, q = l >> 4;
    for (int c = cmin + w; c < NC; c += 4) {
        int t0 = c * 64;
        const __bf16* Cb = Chat + (size_t)(bh * NC + c) * 2048;
        bf16x8 cf[4], sf[4];
        #pragma unroll
        for (int t4 = 0; t4 < 4; t4++) {
            cf[t4] = *(const bf16x8*)(Cb + (t4 * 16 + lm) * 32 + q * 8);
            sf[t4] = *(const bf16x8*)&Spl[c][t4 * 16 + lm][q * 8];
        }
        #pragma unroll
        for (int ti = 0; ti < 4; ti++) {
            #pragma unroll
            for (int tp = 0; tp < 4; tp++) {
                f32x4 y = __builtin_amdgcn_mfma_f32_16x16x32_bf16(cf[ti], sf[tp], (f32x4)0.f, 0, 0, 0);
                #pragma unroll
                for (int r = 0; r < 4; r++) {
                    int i = ti * 16 + q * 4 + r;
                    size_t idx = (rowbase + t0 + i) * DINNER + hd * 64 + tp * 16 + lm;
                    ysD[idx] = (__bf16)((float)ysD[idx] + y[r]);
                }
            }
        }
    }
}

// ---------------- launch ----------------
extern "C" void kernel_launch(void* const* d_in, const int* in_sizes, int n_in,
                              void* d_out, int out_size, void* d_ws, size_t ws_size,
                              hipStream_t stream) {
    const float* x_prefix    = (const float*)d_in[0];
    const float* y_aux       = (const float*)d_in[1];
    const float* pre_conv_w  = (const float*)d_in[2];
    const float* pre_conv_b  = (const float*)d_in[3];
    const float* patch_w     = (const float*)d_in[4];
    const float* patch_b     = (const float*)d_in[5];
    const float* mask_token  = (const float*)d_in[6];
    const float* aux_w       = (const float*)d_in[7];
    const float* aux_b       = (const float*)d_in[8];
    const float* patch_out_w = (const float*)d_in[9];
    const float* patch_out_b = (const float*)d_in[10];
    const float* w_norm[2]   = {(const float*)d_in[11], (const float*)d_in[20]};
    const float* w_inproj[2] = {(const float*)d_in[12], (const float*)d_in[21]};
    const float* w_convw[2]  = {(const float*)d_in[13], (const float*)d_in[22]};
    const float* w_convb[2]  = {(const float*)d_in[14], (const float*)d_in[23]};
    const float* w_dtb[2]    = {(const float*)d_in[15], (const float*)d_in[24]};
    const float* w_alog[2]   = {(const float*)d_in[16], (const float*)d_in[25]};
    const float* w_D[2]      = {(const float*)d_in[17], (const float*)d_in[26]};
    const float* w_gnorm[2]  = {(const float*)d_in[18], (const float*)d_in[27]};
    const float* w_outproj[2]= {(const float*)d_in[19], (const float*)d_in[28]};

    char* p = (char*)d_ws;
    auto alloc = [&](size_t bytes) { char* r = p; p += (bytes + 255) & ~255ULL; return r; };
    __bf16* A_patch  = (__bf16*)alloc((size_t)3072 * 4096 * 2);
    __bf16* WpreT    = (__bf16*)alloc((size_t)256 * 64 * 2);
    __bf16* WtT      = (__bf16*)alloc((size_t)256 * 4096 * 2);
    __bf16* inprojT  = (__bf16*)alloc((size_t)4 * 1152 * 256 * 2);
    __bf16* outprojT = (__bf16*)alloc((size_t)4 * 256 * 512 * 2);
    __bf16* poT      = (__bf16*)alloc((size_t)128 * 512 * 2);
    float*  h_all    = (float*)alloc((size_t)MALL * 256 * 4);
    __bf16* u        = (__bf16*)alloc((size_t)MALL * 256 * 2);
    __bf16* zxb      = (__bf16*)alloc((size_t)MALL * ZXW * 2);
    float*  dtc      = (float*)alloc((size_t)MALL * 8 * 4);
    __bf16* ysD      = (__bf16*)alloc((size_t)MALL * DINNER * 2);
    __bf16* y2       = (__bf16*)alloc((size_t)MALL * DINNER * 2);
    __bf16* ChatF    = (__bf16*)alloc((size_t)64 * 8 * 2048 * 2);
    __bf16* ChatB    = (__bf16*)alloc((size_t)64 * 2 * 2048 * 2);
    float*  dSF      = (float*)alloc((size_t)64 * 8 * 2048 * 4);
    float*  dSB      = (float*)alloc((size_t)64 * 2 * 2048 * 4);
    float*  DcsF     = (float*)alloc((size_t)64 * 8 * 4);
    float*  DcsB     = (float*)alloc((size_t)64 * 2 * 4);

    // 1) prep: weights + d_out bias + h_all background (bias/mask + aux)
    prep_all<<<256 + 1152 + 512 + 64 + 64 + 512 + MALL, 256, 0, stream>>>(
        pre_conv_w, patch_w, w_inproj[0], w_inproj[1], w_outproj[0], w_outproj[1],
        patch_out_w, patch_out_b, y_aux, aux_w, aux_b, patch_b, mask_token,
        WpreT, WtT, inprojT, outprojT, poT, (float*)d_out, h_all);
    // 2) pre-conv GEMM with fused im2row (silu+bf16 -> A_patch)
    preconv_gemm<<<dim3(2, (BSZ * TPREF) / 128), 256, 0, stream>>>(
        x_prefix, WpreT, pre_conv_b, A_patch);
    // 3) patch GEMM: split-K 8, atomicAdd into pre-initialized h_all (row remap)
    gemm_mfma<<<dim3(2, 24, 8), 256, 0, stream>>>(
        A_patch, WtT, h_all, nullptr, 256, 4096, 256, 16);

    for (int i = 0; i < 2; i++) {
        const __bf16* ipTf = inprojT + (size_t)(0 * 2 + i) * 1152 * 256;
        const __bf16* ipTb = inprojT + (size_t)(1 * 2 + i) * 1152 * 256;
        const __bf16* opTf = outprojT + (size_t)(0 * 2 + i) * 256 * 512;
        const __bf16* opTb = outprojT + (size_t)(1 * 2 + i) * 256 * 512;
        rmsnorm_all<<<MALL / 4, 256, 0, stream>>>(h_all, w_norm[0] + i * 256, w_norm[1] + i * 256, u);
        gemm_inproj<<<dim3(9, MALL / 128), 256, 0, stream>>>(u, ipTf, ipTb, zxb, dtc);
        scan_local<<<dim3(80, NHEADS), 256, 0, stream>>>(
            zxb,
            w_convw[0] + i * CONVDIM * 4, w_convb[0] + i * CONVDIM,
            w_convw[1] + i * CONVDIM * 4, w_convb[1] + i * CONVDIM,
            dtc,
            w_dtb[0] + i * 8, w_dtb[1] + i * 8,
            w_alog[0] + i * 8, w_alog[1] + i * 8,
            w_D[0] + i * 8, w_D[1] + i * 8,
            ysD, ChatF, ChatB, dSF, dSB, DcsF, DcsB, i);
        scan_tail<<<128, 256, 0, stream>>>(dSF, dSB, DcsF, DcsB, ChatF, ChatB, ysD, i);
        int gn = (i == 0) ? (MALL / 4) : 512;
        gatednorm_all<<<gn, 256, 0, stream>>>(
            ysD, zxb, w_gnorm[0] + i * DINNER, w_gnorm[1] + i * DINNER, y2, i);
        int oy = (i == 0) ? (MALL / 128) : 16;
        gemm_outproj<<<dim3(2, oy, 2), 256, 0, stream>>>(y2, opTf, opTb, h_all, i);
    }

    // final: fused hcat gather + patch_out GEMM, split-K 8, atomic into bias-initialized d_out
    final_gemm<<<dim3(1, 8, 8), 256, 0, stream>>>(h_all, poT, (float*)d_out);
}

// Round 10
// 317.323 us; speedup vs baseline: 1.1497x; 1.0138x over previous
//
#include <hip/hip_runtime.h>
#include <hip/hip_bf16.h>
#include <math.h>

// ---------------- constants ----------------
#define BSZ      8
#define TPREF    6144
#define CIN      8
#define DMODEL   256
#define DINNER   512
#define DSTATE   32
#define NHEADS   8
#define HEADDIM  64
#define CONVDIM  576
#define DPROJ    1096
#define ZXW      1088              // bf16 zx width (z 0..511 | xBC 512..1087)
#define NTOK     512
#define NVIS     384
#define TBWD     128
#define MFWD     (BSZ * NTOK)      // 4096 rows
#define MBWD     (BSZ * TBWD)      // 1024 rows
#define MALL     (MFWD + MBWD)     // 5120 rows

typedef float f32x4 __attribute__((ext_vector_type(4)));
typedef __bf16 bf16x8 __attribute__((ext_vector_type(8)));

__device__ __forceinline__ float silu_f(float x) { return x / (1.f + expf(-x)); }

#define ASYNC16(gp, lp) \
    __builtin_amdgcn_global_load_lds((const __attribute__((address_space(1))) void*)(gp), \
                                     (__attribute__((address_space(3))) void*)(lp), 16, 0, 0)

// ---------------- generic bf16 MFMA GEMM (NT): C[m,n] = sum_k A[m,k]*Bt[n,k] ----------------
// flags: 2=atomicAdd; 4=silu(v+bias)+bf16 store; 16=atomicAdd into h_all with (b,tok)->row remap
__global__ __launch_bounds__(256) void gemm_mfma(
    const __bf16* __restrict__ A, const __bf16* __restrict__ Bt,
    float* __restrict__ C, const float* __restrict__ bias,
    int N, int K, int ldc, int flags) {
    __shared__ char sm[16384];
    int tid = threadIdx.x;
    int m0 = blockIdx.y * 128, n0 = blockIdx.x * 128;
    int klen = K / gridDim.z;
    int kbeg = blockIdx.z * klen;
    int w = tid >> 6, l = tid & 63;
    int wm = w >> 1, wn = w & 1;
    int lm = l & 15, q = l >> 4;

    f32x4 acc[4][4];
    #pragma unroll
    for (int i = 0; i < 4; i++)
        #pragma unroll
        for (int j = 0; j < 4; j++) acc[i][j] = (f32x4)0.f;

    for (int k0 = 0; k0 < klen; k0 += 32) {
        int kb = kbeg + k0;
        #pragma unroll
        for (int i = 0; i < 2; i++) {
            int s = i * 256 + tid;
            ASYNC16(A + (size_t)(m0 + (s >> 2)) * K + kb + (s & 3) * 8, sm + s * 16);
        }
        #pragma unroll
        for (int i = 0; i < 2; i++) {
            int s = i * 256 + tid;
            ASYNC16(Bt + (size_t)(n0 + (s >> 2)) * K + kb + (s & 3) * 8, sm + 8192 + s * 16);
        }
        __syncthreads();
        bf16x8 af[4], bfr[4];
        #pragma unroll
        for (int mf = 0; mf < 4; mf++)
            af[mf] = *(const bf16x8*)(sm + (wm * 64 + mf * 16 + lm) * 64 + q * 16);
        #pragma unroll
        for (int nf = 0; nf < 4; nf++)
            bfr[nf] = *(const bf16x8*)(sm + 8192 + (wn * 64 + nf * 16 + lm) * 64 + q * 16);
        #pragma unroll
        for (int mf = 0; mf < 4; mf++)
            #pragma unroll
            for (int nf = 0; nf < 4; nf++)
                acc[mf][nf] = __builtin_amdgcn_mfma_f32_16x16x32_bf16(af[mf], bfr[nf], acc[mf][nf], 0, 0, 0);
        __syncthreads();
    }

    #pragma unroll
    for (int mf = 0; mf < 4; mf++) {
        int mbase = m0 + wm * 64 + mf * 16 + q * 4;
        #pragma unroll
        for (int nf = 0; nf < 4; nf++) {
            int n = n0 + wn * 64 + nf * 16 + lm;
            if (n < N) {
                #pragma unroll
                for (int r = 0; r < 4; r++) {
                    float v = acc[mf][nf][r];
                    if (flags & 4) {
                        v = silu_f(v + bias[n]);
                        ((__bf16*)C)[(size_t)(mbase + r) * ldc + n] = (__bf16)v;
                    } else if (flags & 16) {
                        int mm = mbase + r;
                        int bb = mm / NVIS, tk = mm - bb * NVIS;   // m = b*384+tok
                        atomicAdd(C + ((size_t)(bb * NTOK + tk)) * 256 + n, v);
                    } else if (flags & 2) {
                        atomicAdd(C + (size_t)(mbase + r) * ldc + n, v);
                    } else {
                        C[(size_t)(mbase + r) * ldc + n] = v;
                    }
                }
            }
        }
    }
}

// ---------------- pre-conv GEMM with fused im2row ----------------
__global__ __launch_bounds__(256) void preconv_gemm(
    const float* __restrict__ xp, const __bf16* __restrict__ WpreT,
    const float* __restrict__ bias, __bf16* __restrict__ Apatch) {
    __shared__ char sm[32768];   // A: [2][128][32]bf16 = 16KB @0, B: same @16384
    int tid = threadIdx.x;
    int m0 = blockIdx.y * 128, n0 = blockIdx.x * 128;
    int w = tid >> 6, l = tid & 63;
    int wm = w >> 1, wn = w & 1, lm = l & 15, q = l >> 4;

    #pragma unroll
    for (int i = 0; i < 4; i++) {
        int s = i * 256 + tid;
        int kh = s >> 9, row = (s & 511) >> 2, within = s & 3;
        ASYNC16(WpreT + (size_t)(n0 + row) * 64 + kh * 32 + within * 8, sm + 16384 + s * 16);
    }
    if (tid < 128) {
        int m = m0 + tid;
        int b = m / TPREF, t = m - b * TPREF;
        __bf16 d[64];
        #pragma unroll
        for (int j = 40; j < 64; j++) d[j] = (__bf16)0.f;
        #pragma unroll
        for (int k = 0; k < 5; k++) {
            int tt = t - 2 + k;
            bool ok = (tt >= 0) && (tt < TPREF);
            const float* s = xp + ((size_t)b * TPREF + tt) * 8;
            #pragma unroll
            for (int i = 0; i < 8; i++)
                d[i * 5 + k] = ok ? (__bf16)s[i] : (__bf16)0.f;
        }
        uint4* o0 = (uint4*)(sm + tid * 64);
        uint4* o1 = (uint4*)(sm + 8192 + tid * 64);
        #pragma unroll
        for (int k = 0; k < 4; k++) { o0[k] = ((const uint4*)d)[k]; o1[k] = ((const uint4*)d)[4 + k]; }
    }
    __syncthreads();

    f32x4 acc[4][4];
    #pragma unroll
    for (int i = 0; i < 4; i++)
        #pragma unroll
        for (int j = 0; j < 4; j++) acc[i][j] = (f32x4)0.f;
    #pragma unroll
    for (int kh = 0; kh < 2; kh++) {
        bf16x8 af[4], bfr[4];
        #pragma unroll
        for (int mf = 0; mf < 4; mf++)
            af[mf] = *(const bf16x8*)(sm + kh * 8192 + (wm * 64 + mf * 16 + lm) * 64 + q * 16);
        #pragma unroll
        for (int nf = 0; nf < 4; nf++)
            bfr[nf] = *(const bf16x8*)(sm + 16384 + kh * 8192 + (wn * 64 + nf * 16 + lm) * 64 + q * 16);
        #pragma unroll
        for (int mf = 0; mf < 4; mf++)
            #pragma unroll
            for (int nf = 0; nf < 4; nf++)
                acc[mf][nf] = __builtin_amdgcn_mfma_f32_16x16x32_bf16(af[mf], bfr[nf], acc[mf][nf], 0, 0, 0);
    }
    #pragma unroll
    for (int mf = 0; mf < 4; mf++) {
        int mbase = m0 + wm * 64 + mf * 16 + q * 4;
        #pragma unroll
        for (int nf = 0; nf < 4; nf++) {
            int n = n0 + wn * 64 + nf * 16 + lm;
            #pragma unroll
            for (int r = 0; r < 4; r++) {
                float v = silu_f(acc[mf][nf][r] + bias[n]);
                Apatch[(size_t)(mbase + r) * 256 + n] = (__bf16)v;
            }
        }
    }
}

// ---------------- final GEMM: hcat gather fused; split-K 8 (dir x k-quarter) ----------------
__global__ __launch_bounds__(256) void final_gemm(
    const float* __restrict__ h_all, const __bf16* __restrict__ poT,
    float* __restrict__ out) {
    __shared__ __bf16 Asm_[128][40];
    __shared__ char Bsm[8192];
    int tid = threadIdx.x;
    int m0 = blockIdx.y * 128;
    int z = blockIdx.z;                 // 0..7
    int dir = z >> 2, ks = z & 3;
    int koff = ks * 64;
    int w = tid >> 6, l = tid & 63;
    int wm = w >> 1, wn_ = w & 1, lm = l & 15, q = l >> 4;
    f32x4 acc[4][4];
    #pragma unroll
    for (int i = 0; i < 4; i++)
        #pragma unroll
        for (int j = 0; j < 4; j++) acc[i][j] = (f32x4)0.f;

    int r = tid >> 1, half = tid & 1;
    int m = m0 + r;
    int b = m >> 7, jj = m & 127;
    size_t arow = (dir == 0) ? ((size_t)(b * NTOK + NVIS + jj) * 256)
                             : ((size_t)MFWD * 256 + (size_t)(b * TBWD + (TBWD - 1 - jj)) * 256);
    for (int k0 = 0; k0 < 64; k0 += 32) {
        {
            const float4* sp = (const float4*)(h_all + arow + koff + k0 + half * 16);
            float4 v0 = sp[0], v1 = sp[1], v2 = sp[2], v3 = sp[3];
            union { uint4 u; __bf16 hh[8]; } d0, d1;
            d0.hh[0] = (__bf16)v0.x; d0.hh[1] = (__bf16)v0.y; d0.hh[2] = (__bf16)v0.z; d0.hh[3] = (__bf16)v0.w;
            d0.hh[4] = (__bf16)v1.x; d0.hh[5] = (__bf16)v1.y; d0.hh[6] = (__bf16)v1.z; d0.hh[7] = (__bf16)v1.w;
            d1.hh[0] = (__bf16)v2.x; d1.hh[1] = (__bf16)v2.y; d1.hh[2] = (__bf16)v2.z; d1.hh[3] = (__bf16)v2.w;
            d1.hh[4] = (__bf16)v3.x; d1.hh[5] = (__bf16)v3.y; d1.hh[6] = (__bf16)v3.z; d1.hh[7] = (__bf16)v3.w;
            *(uint4*)&Asm_[r][half * 16] = d0.u;
            *(uint4*)&Asm_[r][half * 16 + 8] = d1.u;
        }
        #pragma unroll
        for (int i = 0; i < 2; i++) {
            int s = i * 256 + tid;
            ASYNC16(poT + (size_t)(s >> 2) * 512 + dir * 256 + koff + k0 + (s & 3) * 8, Bsm + s * 16);
        }
        __syncthreads();
        bf16x8 af[4], bfr[4];
        #pragma unroll
        for (int mf = 0; mf < 4; mf++)
            af[mf] = *(const bf16x8*)&Asm_[wm * 64 + mf * 16 + lm][q * 8];
        #pragma unroll
        for (int nf = 0; nf < 4; nf++)
            bfr[nf] = *(const bf16x8*)(Bsm + (wn_ * 64 + nf * 16 + lm) * 64 + q * 16);
        #pragma unroll
        for (int mf = 0; mf < 4; mf++)
            #pragma unroll
            for (int nf = 0; nf < 4; nf++)
                acc[mf][nf] = __builtin_amdgcn_mfma_f32_16x16x32_bf16(af[mf], bfr[nf], acc[mf][nf], 0, 0, 0);
        __syncthreads();
    }
    #pragma unroll
    for (int mf = 0; mf < 4; mf++) {
        int mbase = m0 + wm * 64 + mf * 16 + q * 4;
        #pragma unroll
        for (int nf = 0; nf < 4; nf++) {
            int n = wn_ * 64 + nf * 16 + lm;
            #pragma unroll
            for (int rr = 0; rr < 4; rr++)
                atomicAdd(out + (size_t)(mbase + rr) * 128 + n, acc[mf][nf][rr]);
        }
    }
}

// ---------------- inproj GEMM: 128x128 tile, K=256; bf16 zxb + fp32 dtc outputs ----------------
// layer 0: grid 360 flat (mt = blk/9, nt = blk%9).
// layer 1: grid 264 flat; blk<200: all 40 m-tiles x n-tiles 4..8 (xBC+dt);
//          blk>=200: 16 used-row m-tiles x n-tiles 0..3 (z cols).
__global__ __launch_bounds__(256) void gemm_inproj(
    const __bf16* __restrict__ u, const __bf16* __restrict__ ipTf,
    const __bf16* __restrict__ ipTb, __bf16* __restrict__ zxb, float* __restrict__ dtc,
    int layer) {
    __shared__ char sm[16384];
    int tid = threadIdx.x;
    int blk = blockIdx.x;
    int m0, n0;
    if (layer == 0) {
        m0 = (blk / 9) * 128;
        n0 = (blk % 9) * 128;
    } else if (blk < 200) {
        m0 = (blk / 5) * 128;
        n0 = (4 + blk % 5) * 128;
    } else {
        int r2 = blk - 200;
        int mt = r2 >> 2;            // 0..15
        n0 = (r2 & 3) * 128;
        m0 = (mt < 8) ? (mt * 512 + 384) : (MFWD + (mt - 8) * 128);
    }
    const __bf16* Bt = (m0 >= MFWD) ? ipTb : ipTf;
    int w = tid >> 6, l = tid & 63;
    int wm = w >> 1, wn = w & 1, lm = l & 15, q = l >> 4;
    f32x4 acc[4][4];
    #pragma unroll
    for (int i = 0; i < 4; i++)
        #pragma unroll
        for (int j = 0; j < 4; j++) acc[i][j] = (f32x4)0.f;
    for (int k0 = 0; k0 < 256; k0 += 32) {
        #pragma unroll
        for (int i = 0; i < 2; i++) {
            int s = i * 256 + tid;
            ASYNC16(u + (size_t)(m0 + (s >> 2)) * 256 + k0 + (s & 3) * 8, sm + s * 16);
        }
        #pragma unroll
        for (int i = 0; i < 2; i++) {
            int s = i * 256 + tid;
            ASYNC16(Bt + (size_t)(n0 + (s >> 2)) * 256 + k0 + (s & 3) * 8, sm + 8192 + s * 16);
        }
        __syncthreads();
        bf16x8 af[4], bfr[4];
        #pragma unroll
        for (int mf = 0; mf < 4; mf++)
            af[mf] = *(const bf16x8*)(sm + (wm * 64 + mf * 16 + lm) * 64 + q * 16);
        #pragma unroll
        for (int nf = 0; nf < 4; nf++)
            bfr[nf] = *(const bf16x8*)(sm + 8192 + (wn * 64 + nf * 16 + lm) * 64 + q * 16);
        #pragma unroll
        for (int mf = 0; mf < 4; mf++)
            #pragma unroll
            for (int nf = 0; nf < 4; nf++)
                acc[mf][nf] = __builtin_amdgcn_mfma_f32_16x16x32_bf16(af[mf], bfr[nf], acc[mf][nf], 0, 0, 0);
        __syncthreads();
    }
    #pragma unroll
    for (int mf = 0; mf < 4; mf++) {
        int mbase = m0 + wm * 64 + mf * 16 + q * 4;
        #pragma unroll
        for (int nf = 0; nf < 4; nf++) {
            int n = n0 + wn * 64 + nf * 16 + lm;
            #pragma unroll
            for (int r = 0; r < 4; r++) {
                float v = acc[mf][nf][r];
                if (n < ZXW) zxb[(size_t)(mbase + r) * ZXW + n] = (__bf16)v;
                else if (n < DPROJ) dtc[(size_t)(mbase + r) * 8 + (n - ZXW)] = v;
            }
        }
    }
}

// ---------------- outproj GEMM: 128x128 tile, K=512 split-K 2, layer-aware rows, atomic residual ----------------
__global__ __launch_bounds__(256) void gemm_outproj(
    const __bf16* __restrict__ y2, const __bf16* __restrict__ opTf,
    const __bf16* __restrict__ opTb, float* __restrict__ C, int layer) {
    __shared__ char sm[16384];
    int tid = threadIdx.x;
    int yb = blockIdx.y;
    int m0 = (layer == 0) ? yb * 128
                          : ((yb < 8) ? (yb * 512 + 384) : (MFWD + (yb - 8) * 128));
    int n0 = blockIdx.x * 128;
    int kbeg = blockIdx.z * 256;
    const __bf16* Bt = (m0 >= MFWD) ? opTb : opTf;
    int w = tid >> 6, l = tid & 63;
    int wm = w >> 1, wn = w & 1, lm = l & 15, q = l >> 4;
    f32x4 acc[4][4];
    #pragma unroll
    for (int i = 0; i < 4; i++)
        #pragma unroll
        for (int j = 0; j < 4; j++) acc[i][j] = (f32x4)0.f;
    for (int k0 = 0; k0 < 256; k0 += 32) {
        int kb = kbeg + k0;
        #pragma unroll
        for (int i = 0; i < 2; i++) {
            int s = i * 256 + tid;
            ASYNC16(y2 + (size_t)(m0 + (s >> 2)) * 512 + kb + (s & 3) * 8, sm + s * 16);
        }
        #pragma unroll
        for (int i = 0; i < 2; i++) {
            int s = i * 256 + tid;
            ASYNC16(Bt + (size_t)(n0 + (s >> 2)) * 512 + kb + (s & 3) * 8, sm + 8192 + s * 16);
        }
        __syncthreads();
        bf16x8 af[4], bfr[4];
        #pragma unroll
        for (int mf = 0; mf < 4; mf++)
            af[mf] = *(const bf16x8*)(sm + (wm * 64 + mf * 16 + lm) * 64 + q * 16);
        #pragma unroll
        for (int nf = 0; nf < 4; nf++)
            bfr[nf] = *(const bf16x8*)(sm + 8192 + (wn * 64 + nf * 16 + lm) * 64 + q * 16);
        #pragma unroll
        for (int mf = 0; mf < 4; mf++)
            #pragma unroll
            for (int nf = 0; nf < 4; nf++)
                acc[mf][nf] = __builtin_amdgcn_mfma_f32_16x16x32_bf16(af[mf], bfr[nf], acc[mf][nf], 0, 0, 0);
        __syncthreads();
    }
    #pragma unroll
    for (int mf = 0; mf < 4; mf++) {
        int mbase = m0 + wm * 64 + mf * 16 + q * 4;
        #pragma unroll
        for (int nf = 0; nf < 4; nf++) {
            int n = n0 + wn * 64 + nf * 16 + lm;
            #pragma unroll
            for (int r = 0; r < 4; r++) {
                size_t ci = (size_t)(mbase + r) * DMODEL + n;
                atomicAdd(C + ci, acc[mf][nf][r]);
            }
        }
    }
}

// ---------------- elementwise norms ----------------
__global__ __launch_bounds__(256) void rmsnorm_all(
    const float* __restrict__ h, const float* __restrict__ wf,
    const float* __restrict__ wb, __bf16* __restrict__ u) {
    int row = blockIdx.x * 4 + (threadIdx.x >> 6);
    int lane = threadIdx.x & 63;
    const float* w = (row >= MFWD) ? wb : wf;
    float4 v = ((const float4*)(h + (size_t)row * 256))[lane];
    float ss = v.x * v.x + v.y * v.y + v.z * v.z + v.w * v.w;
    #pragma unroll
    for (int off = 32; off >= 1; off >>= 1) ss += __shfl_xor(ss, off);
    float rs = rsqrtf(ss * (1.f / 256.f) + 1e-5f);
    float4 wv = ((const float4*)w)[lane];
    __bf16 o4[4] = {(__bf16)(v.x * rs * wv.x), (__bf16)(v.y * rs * wv.y),
                    (__bf16)(v.z * rs * wv.z), (__bf16)(v.w * rs * wv.w)};
    *(uint2*)(u + (size_t)row * 256 + lane * 4) = *(uint2*)o4;
}

// gatednorm: layer 0 covers all rows (grid 1280); layer 1 covers only the 2048
// rows consumed by outproj layer 1 (grid 512): fwd rows b*512+384..511, all bwd rows.
__global__ __launch_bounds__(256) void gatednorm_all(
    const __bf16* __restrict__ ysD, const __bf16* __restrict__ zxb,
    const float* __restrict__ gwf, const float* __restrict__ gwb,
    __bf16* __restrict__ y2, int layer) {
    int blk = blockIdx.x;
    int sub = threadIdx.x >> 6;
    int row;
    if (layer == 0) {
        row = blk * 4 + sub;
    } else {
        if (blk < 256) { int b = blk >> 5; row = b * 512 + 384 + (blk & 31) * 4 + sub; }
        else           { row = MFWD + (blk - 256) * 4 + sub; }
    }
    int lane = threadIdx.x & 63;
    const float* gw = (row >= MFWD) ? gwb : gwf;
    union { uint4 u; __bf16 hh[8]; } yv, zv;
    yv.u = *(const uint4*)(ysD + (size_t)row * 512 + lane * 8);
    zv.u = *(const uint4*)(zxb + (size_t)row * ZXW + lane * 8);
    float g[8];
    #pragma unroll
    for (int j = 0; j < 8; j++) g[j] = (float)yv.hh[j] * silu_f((float)zv.hh[j]);
    float ss = 0.f;
    #pragma unroll
    for (int j = 0; j < 8; j++) ss += g[j] * g[j];
    #pragma unroll
    for (int off = 32; off >= 1; off >>= 1) ss += __shfl_xor(ss, off);
    float rs = rsqrtf(ss * (1.f / 512.f) + 1e-5f);
    const float4* gr = (const float4*)(gw + lane * 8);
    float4 g0 = gr[0], g1 = gr[1];
    union { uint4 u; __bf16 hh[8]; } d;
    d.hh[0] = (__bf16)(g[0] * rs * g0.x); d.hh[1] = (__bf16)(g[1] * rs * g0.y);
    d.hh[2] = (__bf16)(g[2] * rs * g0.z); d.hh[3] = (__bf16)(g[3] * rs * g0.w);
    d.hh[4] = (__bf16)(g[4] * rs * g1.x); d.hh[5] = (__bf16)(g[5] * rs * g1.y);
    d.hh[6] = (__bf16)(g[6] * rs * g1.z); d.hh[7] = (__bf16)(g[7] * rs * g1.w);
    *(uint4*)(y2 + (size_t)row * 512 + lane * 8) = d.u;
}

// ---------------- segmented prep kernel (all coalesced) ----------------
// WtT 256 | inprojT 1152 | outprojT 512 | poT 64 | WpreT 64 | dout 512 | hinit 5120
__global__ void prep_all(const float* __restrict__ pre_conv_w, const float* __restrict__ patch_w,
                         const float* __restrict__ ip0, const float* __restrict__ ip1,
                         const float* __restrict__ op0, const float* __restrict__ op1,
                         const float* __restrict__ pow_, const float* __restrict__ pob,
                         const float* __restrict__ y_aux, const float* __restrict__ aux_w,
                         const float* __restrict__ aux_b,
                         const float* __restrict__ patch_b, const float* __restrict__ mtok,
                         __bf16* __restrict__ WpreT, __bf16* __restrict__ WtT,
                         __bf16* __restrict__ inprojT, __bf16* __restrict__ outprojT,
                         __bf16* __restrict__ poT, float* __restrict__ dout,
                         float* __restrict__ h_all) {
    __shared__ float tile[32][33];
    int bx = blockIdx.x, tid = threadIdx.x;
    int tx = tid & 31, ty = tid >> 5;
    if (bx < 256) {
        int o = bx, c = tid;
        float f[16];
        const float4* s = (const float4*)(patch_w + (size_t)o * 4096 + c * 16);
        #pragma unroll
        for (int j = 0; j < 4; j++) *(float4*)&f[j * 4] = s[j];
        #pragma unroll
        for (int k = 0; k < 16; k++)
            WtT[(size_t)o * 4096 + k * 256 + c] = (__bf16)f[k];
        return;
    }
    bx -= 256;
    if (bx < 1152) {
        int seg = bx / 288, rem = bx % 288;
        int n0 = (rem / 8) * 32, k0 = (rem % 8) * 32;
        const float* src = (seg < 2 ? ip0 : ip1) + (size_t)(seg & 1) * 256 * DPROJ;
        #pragma unroll
        for (int j = 0; j < 4; j++) {
            int r = ty + j * 8;
            int n = n0 + tx;
            tile[r][tx] = (n < DPROJ) ? src[(size_t)(k0 + r) * DPROJ + n] : 0.f;
        }
        __syncthreads();
        __bf16* dst = inprojT + (size_t)seg * 1152 * 256;
        #pragma unroll
        for (int j = 0; j < 4; j++) {
            int r = ty + j * 8;
            dst[(size_t)(n0 + r) * 256 + k0 + tx] = (__bf16)tile[tx][r];
        }
        return;
    }
    bx -= 1152;
    if (bx < 512) {
        int s = bx / 128, rem = bx % 128;
        int n0 = (rem / 16) * 32, k0 = (rem % 16) * 32;
        const float* src = (s < 2 ? op0 : op1) + (size_t)(s & 1) * DINNER * DMODEL;
        #pragma unroll
        for (int j = 0; j < 4; j++) {
            int r = ty + j * 8;
            tile[r][tx] = src[(size_t)(k0 + r) * 256 + n0 + tx];
        }
        __syncthreads();
        __bf16* dst = outprojT + (size_t)s * 256 * 512;
        #pragma unroll
        for (int j = 0; j < 4; j++) {
            int r = ty + j * 8;
            dst[(size_t)(n0 + r) * 512 + k0 + tx] = (__bf16)tile[tx][r];
        }
        return;
    }
    bx -= 512;
    if (bx < 64) {
        int n0 = (bx / 16) * 32, k0 = (bx % 16) * 32;
        #pragma unroll
        for (int j = 0; j < 4; j++) {
            int r = ty + j * 8;
            tile[r][tx] = pow_[(size_t)(k0 + r) * 128 + n0 + tx];
        }
        __syncthreads();
        #pragma unroll
        for (int j = 0; j < 4; j++) {
            int r = ty + j * 8;
            poT[(size_t)(n0 + r) * 512 + k0 + tx] = (__bf16)tile[tx][r];
        }
        return;
    }
    bx -= 64;
    if (bx < 64) {
        int idx = bx * 256 + tid;
        int o = idx >> 6, kk = idx & 63;
        WpreT[idx] = (kk < 40) ? (__bf16)pre_conv_w[o * 40 + kk] : (__bf16)0.f;
        return;
    }
    bx -= 64;
    if (bx < 512) {
        int idx = bx * 256 + tid;
        dout[idx] = pob[idx & 127];
        return;
    }
    bx -= 512;
    {   // h_all init: visible fwd rows = patch_b+aux (GEMM atomically adds patch term);
        // masked fwd rows and all bwd rows = mask_token+aux
        int row = bx, o = tid;
        int b; bool masked;
        if (row < MFWD) { b = row >> 9; int tok = row & 511; masked = (tok >= NVIS); }
        else { b = (row - MFWD) >> 7; masked = true; }
        float acc = aux_b[o];
        #pragma unroll
        for (int i = 0; i < 16; i++) acc += y_aux[b * 16 + i] * aux_w[i * 256 + o];
        float v = (masked ? mtok[o] : patch_b[o]) + silu_f(acc);
        h_all[(size_t)row * 256 + o] = v;
    }
}

// ---------------- chunked SSD scan phase A with fused depthwise conv: 4 waves/block ----------------
// grid (80, 8). Stages raw X/BC slices from zxb cooperatively (uint4), conv k=4 + silu in-block.
__global__ __launch_bounds__(256) void scan_local(
    const __bf16* __restrict__ zxb,
    const float* __restrict__ cwf, const float* __restrict__ cbf,
    const float* __restrict__ cwb, const float* __restrict__ cbb,
    const float* __restrict__ dtc,
    const float* __restrict__ dtbf, const float* __restrict__ dtbb,
    const float* __restrict__ Alogf, const float* __restrict__ Alogb,
    const float* __restrict__ Dpf, const float* __restrict__ Dpb,
    __bf16* __restrict__ ysD,
    __bf16* __restrict__ ChatF, __bf16* __restrict__ ChatB,
    float* __restrict__ dSF, float* __restrict__ dSB,
    float* __restrict__ DcsF, float* __restrict__ DcsB, int layer) {
    int id = blockIdx.x, hd = blockIdx.y;
    int b, c, T, NC; size_t rowbase;
    __bf16* Chat; float *dS, *Dcs;
    const float *dtb, *Alog, *Dp, *cw, *cb;
    if (id < 64) { b = id >> 3; c = id & 7; T = NTOK; NC = 8; rowbase = (size_t)b * NTOK;
                   Chat = ChatF; dS = dSF; Dcs = DcsF;
                   dtb = dtbf; Alog = Alogf; Dp = Dpf; cw = cwf; cb = cbf; }
    else { int i2 = id - 64; b = i2 >> 1; c = i2 & 1; T = TBWD; NC = 2;
           rowbase = (size_t)MFWD + (size_t)b * TBWD;
           Chat = ChatB; dS = dSB; Dcs = DcsB;
           dtb = dtbb; Alog = Alogb; Dp = Dpb; cw = cwb; cb = cbb; }
    bool skipY = (layer == 1) && (id < 64) && (c < 6);
    int bh = b * 8 + hd;
    int t0 = c * 64;
    int tid = threadIdx.x;
    int w = tid >> 6, l = tid & 63;
    int lm = l & 15, q = l >> 4;
    float A = -expf(Alog[hd]);
    float Dh = Dp[hd];

    __shared__ char smem[40704];
    __bf16 (*Xl)[72]  = (__bf16(*)[72])(smem);            // Xl[ch][t] post-conv
    __bf16 (*BCl)[72] = (__bf16(*)[72])(smem + 9216);     // BCl[t][ch] post-conv
    __bf16 (*Pl)[72]  = (__bf16(*)[72])(smem + 9216);     // overwrites BCl after reads done
    __bf16 (*Wbl)[72] = (__bf16(*)[72])(smem + 18432);
    float* lcs = (float*)(smem + 23040);
    float* dts = (float*)(smem + 23296);
    __bf16 (*xraw)[64] = (__bf16(*)[64])(smem + 23552);   // 67x64 raw X (this head)
    __bf16 (*braw)[64] = (__bf16(*)[64])(smem + 32128);   // 67x64 raw BC

    // ---- stage raw slices: 1072 uint4 chunks over 256 threads ----
    for (int s = tid; s < 1072; s += 256) {
        int arr = (s >= 536) ? 1 : 0;
        int s2 = s - arr * 536;
        int r = s2 >> 3, seg = s2 & 7;
        int t = t0 - 3 + r;
        uint4 v = make_uint4(0u, 0u, 0u, 0u);
        if (t >= 0) {
            size_t col = arr ? (size_t)(1024 + seg * 8) : (size_t)(DINNER + hd * 64 + seg * 8);
            v = *(const uint4*)(zxb + (rowbase + t) * (size_t)ZXW + col);
        }
        if (arr) *(uint4*)&braw[r][seg * 8] = v;
        else     *(uint4*)&xraw[r][seg * 8] = v;
    }
    __syncthreads();

    // ---- conv X: ch = lane, t-quarter = wave; pack 16 outputs -> Xl[ch][t] ----
    {
        int cX = hd * 64 + l;
        float w0 = cw[cX * 4], w1 = cw[cX * 4 + 1], w2 = cw[cX * 4 + 2], w3 = cw[cX * 4 + 3];
        float cbv = cb[cX];
        int tb = w * 16;
        float a0 = (float)xraw[tb][l], a1 = (float)xraw[tb + 1][l], a2 = (float)xraw[tb + 2][l];
        union { uint4 u; __bf16 h[8]; } p0, p1;
        #pragma unroll
        for (int j = 0; j < 16; j++) {
            float a3 = (float)xraw[tb + j + 3][l];
            float acc = cbv + w0 * a0 + w1 * a1 + w2 * a2 + w3 * a3;
            if (j < 8) p0.h[j] = (__bf16)silu_f(acc);
            else       p1.h[j - 8] = (__bf16)silu_f(acc);
            a0 = a1; a1 = a2; a2 = a3;
        }
        *(uint4*)&Xl[l][tb]     = p0.u;
        *(uint4*)&Xl[l][tb + 8] = p1.u;
    }
    // ---- conv BC: ch = lane, t-quarter = wave -> BCl[t][ch] (transposed, scalar stores) ----
    {
        int cc = 512 + l;
        float w0 = cw[cc * 4], w1 = cw[cc * 4 + 1], w2 = cw[cc * 4 + 2], w3 = cw[cc * 4 + 3];
        float cbv = cb[cc];
        int tb = w * 16;
        float a0 = (float)braw[tb][l], a1 = (float)braw[tb + 1][l], a2 = (float)braw[tb + 2][l];
        #pragma unroll
        for (int j = 0; j < 16; j++) {
            float a3 = (float)braw[tb + j + 3][l];
            float acc = cbv + w0 * a0 + w1 * a1 + w2 * a2 + w3 * a3;
            BCl[tb + j][l] = (__bf16)silu_f(acc);
            a0 = a1; a1 = a2; a2 = a3;
        }
    }
    // ---- per-token dt + cumulative log-decay (redundant per wave; lane = token) ----
    float xdt = dtc[(rowbase + t0 + l) * 8 + hd] + dtb[hd];
    float dtv = (xdt > 20.f) ? xdt : log1pf(expf(xdt));
    float lc = A * dtv;
    #pragma unroll
    for (int off = 1; off < 64; off <<= 1) {
        float o = __shfl_up(lc, off);
        if (l >= off) lc += o;
    }
    float lc63 = __shfl(lc, 63);
    float wj = expf(lc63 - lc) * dtv;
    float eli = expf(lc);
    if (w == 0) {
        lcs[l] = lc; dts[l] = dtv;
        if (l == 0) Dcs[bh * NC + c] = expf(lc63);
    }
    __syncthreads();   // conv outputs + lcs/dts visible

    // ---- Chat write (wave w: channel group w*8..w*8+7 of C part) ----
    if (!skipY) {
        union { uint4 u; __bf16 h[8]; } s, d;
        s.u = *(const uint4*)&BCl[l][32 + w * 8];
        #pragma unroll
        for (int j = 0; j < 8; j++) d.h[j] = (__bf16)(eli * (float)s.h[j]);
        *(uint4*)(Chat + ((size_t)(bh * NC + c) * 64 + l) * 32 + w * 8) = d.u;
    }
    // ---- Wbl[n][t] build (wave w: n group w*8..w*8+7) ----
    {
        union { uint4 u; __bf16 h[8]; } s;
        s.u = *(const uint4*)&BCl[l][w * 8];
        #pragma unroll
        for (int j = 0; j < 8; j++) Wbl[w * 8 + j][l] = (__bf16)(wj * (float)s.h[j]);
    }
    // ---- P-phase register loads (must complete before Pl overwrites BCl) ----
    bf16x8 cfr, bfr[4];
    if (!skipY) {
        cfr = *(const bf16x8*)&BCl[w * 16 + lm][32 + q * 8];
        #pragma unroll
        for (int tj = 0; tj < 4; tj++)
            if (tj <= w) bfr[tj] = *(const bf16x8*)&BCl[tj * 16 + lm][q * 8];
    }
    __syncthreads();   // all BCl reads done; Wbl complete

    if (!skipY) {
        float lci[4];
        #pragma unroll
        for (int r = 0; r < 4; r++) lci[r] = lcs[w * 16 + q * 4 + r];
        #pragma unroll
        for (int tj = 0; tj < 4; tj++) {
            if (tj > w) {
                #pragma unroll
                for (int r = 0; r < 4; r++) Pl[w * 16 + q * 4 + r][tj * 16 + lm] = (__bf16)0.f;
                continue;
            }
            f32x4 g = __builtin_amdgcn_mfma_f32_16x16x32_bf16(cfr, bfr[tj], (f32x4)0.f, 0, 0, 0);
            int j = tj * 16 + lm;
            float lcj = lcs[j], dtj = dts[j];
            #pragma unroll
            for (int r = 0; r < 4; r++) {
                int i = w * 16 + q * 4 + r;
                float v = (j <= i) ? g[r] * expf(lci[r] - lcj) * dtj : 0.f;
                if (j == i) v += Dh;
                Pl[i][j] = (__bf16)v;
            }
        }
    }
    __syncthreads();   // Pl ready

    bf16x8 xf0[4], xf1[4];
    #pragma unroll
    for (int t4 = 0; t4 < 4; t4++) {
        xf0[t4] = *(const bf16x8*)&Xl[t4 * 16 + lm][q * 8];
        xf1[t4] = *(const bf16x8*)&Xl[t4 * 16 + lm][32 + q * 8];
    }
    if (!skipY) {
        bf16x8 pf0 = *(const bf16x8*)&Pl[w * 16 + lm][q * 8];
        bf16x8 pf1 = *(const bf16x8*)&Pl[w * 16 + lm][32 + q * 8];
        #pragma unroll
        for (int tp = 0; tp < 4; tp++) {
            f32x4 y = __builtin_amdgcn_mfma_f32_16x16x32_bf16(pf0, xf0[tp], (f32x4)0.f, 0, 0, 0);
            y = __builtin_amdgcn_mfma_f32_16x16x32_bf16(pf1, xf1[tp], y, 0, 0, 0);
            #pragma unroll
            for (int r = 0; r < 4; r++) {
                int i = w * 16 + q * 4 + r;
                ysD[(rowbase + t0 + i) * DINNER + hd * 64 + tp * 16 + lm] = (__bf16)y[r];
            }
        }
    }
    // ---- dS (wave w = tp) ----
    bf16x8 wf0[2], wf1[2];
    #pragma unroll
    for (int tn = 0; tn < 2; tn++) {
        wf0[tn] = *(const bf16x8*)&Wbl[tn * 16 + lm][q * 8];
        wf1[tn] = *(const bf16x8*)&Wbl[tn * 16 + lm][32 + q * 8];
    }
    float* dso = dS + (size_t)(bh * NC + c) * 2048;
    #pragma unroll
    for (int tn = 0; tn < 2; tn++) {
        f32x4 s = __builtin_amdgcn_mfma_f32_16x16x32_bf16(xf0[w], wf0[tn], (f32x4)0.f, 0, 0, 0);
        s = __builtin_amdgcn_mfma_f32_16x16x32_bf16(xf1[w], wf1[tn], s, 0, 0, 0);
        #pragma unroll
        for (int r = 0; r < 4; r++) {
            int pp = w * 16 + q * 4 + r, nn = tn * 16 + lm;
            dso[pp * 32 + nn] = s[r];
        }
    }
}

// ---------------- scan tail: recurrence + cross-chunk Y add ----------------
__global__ __launch_bounds__(256) void scan_tail(
    const float* __restrict__ dSF, const float* __restrict__ dSB,
    const float* __restrict__ DcsF, const float* __restrict__ DcsB,
    const __bf16* __restrict__ ChatF, const __bf16* __restrict__ ChatB,
    __bf16* __restrict__ ysD, int layer) {
    int blk = blockIdx.x;
    int dir = blk >= 64;
    int bh = blk & 63;
    int NC = dir ? 2 : 8;
    int T = dir ? TBWD : NTOK;
    int b = bh >> 3, hd = bh & 7;
    size_t rowbase = dir ? ((size_t)MFWD + (size_t)b * TBWD) : ((size_t)b * NTOK);
    const float* dS = dir ? dSB : dSF;
    const float* Dcs = dir ? DcsB : DcsF;
    const __bf16* Chat = dir ? ChatB : ChatF;
    int cmin = (layer == 1 && !dir) ? 6 : 1;
    int tid = threadIdx.x;
    __shared__ __bf16 Spl[8][64][40];
    {
        int p = tid >> 2, n0 = (tid & 3) * 8;
        float S[8];
        #pragma unroll
        for (int j = 0; j < 8; j++) S[j] = 0.f;
        for (int c = 0; c < NC; c++) {
            union { uint4 u; __bf16 hh[8]; } o;
            #pragma unroll
            for (int j = 0; j < 8; j++) o.hh[j] = (__bf16)S[j];
            *(uint4*)&Spl[c][p][n0] = o.u;
            float Dc = Dcs[bh * NC + c];
            const float4* dp = (const float4*)(dS + ((size_t)(bh * NC + c)) * 2048 + tid * 8);
            float4 d0 = dp[0], d1 = dp[1];
            S[0] = Dc * S[0] + d0.x; S[1] = Dc * S[1] + d0.y;
            S[2] = Dc * S[2] + d0.z; S[3] = Dc * S[3] + d0.w;
            S[4] = Dc * S[4] + d1.x; S[5] = Dc * S[5] + d1.y;
            S[6] = Dc * S[6] + d1.z; S[7] = Dc * S[7] + d1.w;
        }
    }
    __syncthreads();
    int w = tid >> 6, l = tid & 63, lm = l & 15, q = l >> 4;
    for (int c = cmin + w; c < NC; c += 4) {
        int t0 = c * 64;
        const __bf16* Cb = Chat + (size_t)(bh * NC + c) * 2048;
        bf16x8 cf[4], sf[4];
        #pragma unroll
        for (int t4 = 0; t4 < 4; t4++) {
            cf[t4] = *(const bf16x8*)(Cb + (t4 * 16 + lm) * 32 + q * 8);
            sf[t4] = *(const bf16x8*)&Spl[c][t4 * 16 + lm][q * 8];
        }
        #pragma unroll
        for (int ti = 0; ti < 4; ti++) {
            #pragma unroll
            for (int tp = 0; tp < 4; tp++) {
                f32x4 y = __builtin_amdgcn_mfma_f32_16x16x32_bf16(cf[ti], sf[tp], (f32x4)0.f, 0, 0, 0);
                #pragma unroll
                for (int r = 0; r < 4; r++) {
                    int i = ti * 16 + q * 4 + r;
                    size_t idx = (rowbase + t0 + i) * DINNER + hd * 64 + tp * 16 + lm;
                    ysD[idx] = (__bf16)((float)ysD[idx] + y[r]);
                }
            }
        }
    }
}

// ---------------- launch ----------------
extern "C" void kernel_launch(void* const* d_in, const int* in_sizes, int n_in,
                              void* d_out, int out_size, void* d_ws, size_t ws_size,
                              hipStream_t stream) {
    const float* x_prefix    = (const float*)d_in[0];
    const float* y_aux       = (const float*)d_in[1];
    const float* pre_conv_w  = (const float*)d_in[2];
    const float* pre_conv_b  = (const float*)d_in[3];
    const float* patch_w     = (const float*)d_in[4];
    const float* patch_b     = (const float*)d_in[5];
    const float* mask_token  = (const float*)d_in[6];
    const float* aux_w       = (const float*)d_in[7];
    const float* aux_b       = (const float*)d_in[8];
    const float* patch_out_w = (const float*)d_in[9];
    const float* patch_out_b = (const float*)d_in[10];
    const float* w_norm[2]   = {(const float*)d_in[11], (const float*)d_in[20]};
    const float* w_inproj[2] = {(const float*)d_in[12], (const float*)d_in[21]};
    const float* w_convw[2]  = {(const float*)d_in[13], (const float*)d_in[22]};
    const float* w_convb[2]  = {(const float*)d_in[14], (const float*)d_in[23]};
    const float* w_dtb[2]    = {(const float*)d_in[15], (const float*)d_in[24]};
    const float* w_alog[2]   = {(const float*)d_in[16], (const float*)d_in[25]};
    const float* w_D[2]      = {(const float*)d_in[17], (const float*)d_in[26]};
    const float* w_gnorm[2]  = {(const float*)d_in[18], (const float*)d_in[27]};
    const float* w_outproj[2]= {(const float*)d_in[19], (const float*)d_in[28]};

    char* p = (char*)d_ws;
    auto alloc = [&](size_t bytes) { char* r = p; p += (bytes + 255) & ~255ULL; return r; };
    __bf16* A_patch  = (__bf16*)alloc((size_t)3072 * 4096 * 2);
    __bf16* WpreT    = (__bf16*)alloc((size_t)256 * 64 * 2);
    __bf16* WtT      = (__bf16*)alloc((size_t)256 * 4096 * 2);
    __bf16* inprojT  = (__bf16*)alloc((size_t)4 * 1152 * 256 * 2);
    __bf16* outprojT = (__bf16*)alloc((size_t)4 * 256 * 512 * 2);
    __bf16* poT      = (__bf16*)alloc((size_t)128 * 512 * 2);
    float*  h_all    = (float*)alloc((size_t)MALL * 256 * 4);
    __bf16* u        = (__bf16*)alloc((size_t)MALL * 256 * 2);
    __bf16* zxb      = (__bf16*)alloc((size_t)MALL * ZXW * 2);
    float*  dtc      = (float*)alloc((size_t)MALL * 8 * 4);
    __bf16* ysD      = (__bf16*)alloc((size_t)MALL * DINNER * 2);
    __bf16* y2       = (__bf16*)alloc((size_t)MALL * DINNER * 2);
    __bf16* ChatF    = (__bf16*)alloc((size_t)64 * 8 * 2048 * 2);
    __bf16* ChatB    = (__bf16*)alloc((size_t)64 * 2 * 2048 * 2);
    float*  dSF      = (float*)alloc((size_t)64 * 8 * 2048 * 4);
    float*  dSB      = (float*)alloc((size_t)64 * 2 * 2048 * 4);
    float*  DcsF     = (float*)alloc((size_t)64 * 8 * 4);
    float*  DcsB     = (float*)alloc((size_t)64 * 2 * 4);

    // 1) prep: weights + d_out bias + h_all background (bias/mask + aux)
    prep_all<<<256 + 1152 + 512 + 64 + 64 + 512 + MALL, 256, 0, stream>>>(
        pre_conv_w, patch_w, w_inproj[0], w_inproj[1], w_outproj[0], w_outproj[1],
        patch_out_w, patch_out_b, y_aux, aux_w, aux_b, patch_b, mask_token,
        WpreT, WtT, inprojT, outprojT, poT, (float*)d_out, h_all);
    // 2) pre-conv GEMM with fused im2row (silu+bf16 -> A_patch)
    preconv_gemm<<<dim3(2, (BSZ * TPREF) / 128), 256, 0, stream>>>(
        x_prefix, WpreT, pre_conv_b, A_patch);
    // 3) patch GEMM: split-K 8, atomicAdd into pre-initialized h_all (row remap)
    gemm_mfma<<<dim3(2, 24, 8), 256, 0, stream>>>(
        A_patch, WtT, h_all, nullptr, 256, 4096, 256, 16);

    for (int i = 0; i < 2; i++) {
        const __bf16* ipTf = inprojT + (size_t)(0 * 2 + i) * 1152 * 256;
        const __bf16* ipTb = inprojT + (size_t)(1 * 2 + i) * 1152 * 256;
        const __bf16* opTf = outprojT + (size_t)(0 * 2 + i) * 256 * 512;
        const __bf16* opTb = outprojT + (size_t)(1 * 2 + i) * 256 * 512;
        rmsnorm_all<<<MALL / 4, 256, 0, stream>>>(h_all, w_norm[0] + i * 256, w_norm[1] + i * 256, u);
        int ipg = (i == 0) ? 360 : 264;
        gemm_inproj<<<ipg, 256, 0, stream>>>(u, ipTf, ipTb, zxb, dtc, i);
        scan_local<<<dim3(80, NHEADS), 256, 0, stream>>>(
            zxb,
            w_convw[0] + i * CONVDIM * 4, w_convb[0] + i * CONVDIM,
            w_convw[1] + i * CONVDIM * 4, w_convb[1] + i * CONVDIM,
            dtc,
            w_dtb[0] + i * 8, w_dtb[1] + i * 8,
            w_alog[0] + i * 8, w_alog[1] + i * 8,
            w_D[0] + i * 8, w_D[1] + i * 8,
            ysD, ChatF, ChatB, dSF, dSB, DcsF, DcsB, i);
        scan_tail<<<128, 256, 0, stream>>>(dSF, dSB, DcsF, DcsB, ChatF, ChatB, ysD, i);
        int gn = (i == 0) ? (MALL / 4) : 512;
        gatednorm_all<<<gn, 256, 0, stream>>>(
            ysD, zxb, w_gnorm[0] + i * DINNER, w_gnorm[1] + i * DINNER, y2, i);
        int oy = (i == 0) ? (MALL / 128) : 16;
        gemm_outproj<<<dim3(2, oy, 2), 256, 0, stream>>>(y2, opTf, opTb, h_all, i);
    }

    // final: fused hcat gather + patch_out GEMM, split-K 8, atomic into bias-initialized d_out
    final_gemm<<<dim3(1, 8, 8), 256, 0, stream>>>(h_all, poT, (float*)d_out);
}